// Round 6
// baseline (471.764 us; speedup 1.0000x reference)
//
#include <hip/hip_runtime.h>
#include <hip/hip_bf16.h>
#include <math.h>

#define NTOK 8192
#define DM 512
#define DFF 2048
#define NE 8
#define ROWCAP 34816   // 32768 assignments max + 8*256 granule padding

typedef __attribute__((ext_vector_type(8))) short bfrag;
typedef __attribute__((ext_vector_type(4))) float f32x4;
typedef __attribute__((ext_vector_type(4))) unsigned int u32x4;
typedef __attribute__((ext_vector_type(4))) short s16x4;

// async global->LDS, 16B/lane; LDS dest = wave-uniform base + lane*16 (global addr may be per-lane)
#define GLD_LDS16(gp, lp) __builtin_amdgcn_global_load_lds( \
    (const __attribute__((address_space(1))) void*)(gp),    \
    (__attribute__((address_space(3))) void*)(lp), 16, 0, 0)

// LDS byte offset of a generic pointer known to point into LDS
#define LDS_OFF(p) ((unsigned)(size_t)(__attribute__((address_space(3))) void*)(p))

// raw workgroup barrier WITHOUT the implicit s_waitcnt vmcnt(0) that __syncthreads carries.
__device__ __forceinline__ void wg_barrier() {
  asm volatile("" ::: "memory");
  __builtin_amdgcn_sched_barrier(0);
  __builtin_amdgcn_s_barrier();
  __builtin_amdgcn_sched_barrier(0);
  asm volatile("" ::: "memory");
}

// inline-asm ds_read_b128: invisible to the compiler's waitcnt pass, so no implicit
// vmcnt(0) drain is inserted to order it against pending global_load_lds DMA.
// Caller MUST fence with s_waitcnt lgkmcnt(0) + sched_barrier(0) before consuming.
__device__ __forceinline__ bfrag lds_read_b128(unsigned addr) {
  bfrag r;
  asm volatile("ds_read_b128 %0, %1" : "=v"(r) : "v"(addr));
  return r;
}

__device__ __forceinline__ short f2bf(float f) {
  unsigned u = __builtin_bit_cast(unsigned, f);
  u += 0x7fffu + ((u >> 16) & 1u);
  return (short)(u >> 16);
}
__device__ __forceinline__ float bf2f(short s) {
  unsigned u = ((unsigned)(unsigned short)s) << 16;
  return __builtin_bit_cast(float, u);
}
// tanh-form GELU via hw exp2+rcp (~7 ops). max |diff vs erf-gelu| ~5e-4.
__device__ __forceinline__ float fast_gelu(float v) {
  float u = fmaf(v * v * v, 0.044715f, v) * 0.7978845608f;
  float ex = __builtin_amdgcn_exp2f(u * -2.8853900818f);
  return v * __builtin_amdgcn_rcpf(1.f + ex);
}

// ---------------- fp32 -> bf16 conversion ----------------
__global__ __launch_bounds__(256) void cvt_kernel(const float* __restrict__ in,
                                                  short* __restrict__ o, int n4) {
  int i = blockIdx.x * 256 + threadIdx.x;
  if (i >= n4) return;
  f32x4 v = ((const f32x4*)in)[i];
  s16x4 s;
  #pragma unroll
  for (int j = 0; j < 4; j++) s[j] = f2bf(v[j]);
  ((s16x4*)o)[i] = s;
}

// ---------------- fp32 -> bf16 transpose-convert ----------------
__global__ __launch_bounds__(256) void cvtT_kernel(const float* __restrict__ in,
                                                   short* __restrict__ o, int R, int C) {
  __shared__ float t[32][33];
  size_t eoff = (size_t)blockIdx.z * R * C;
  in += eoff; o += eoff;
  int r0 = blockIdx.x * 32, c0 = blockIdx.y * 32;
  int tx = threadIdx.x & 31, ty = threadIdx.x >> 5;
  #pragma unroll
  for (int i = 0; i < 32; i += 8)
    t[ty + i][tx] = in[(size_t)(r0 + ty + i) * C + c0 + tx];
  __syncthreads();
  #pragma unroll
  for (int i = 0; i < 32; i += 8)
    o[(size_t)(c0 + ty + i) * R + r0 + tx] = f2bf(t[tx][ty + i]);
}

// ---------------- router ----------------
__global__ __launch_bounds__(256) void router_kernel(const float* __restrict__ x,
                                                     const float* __restrict__ rw,
                                                     int* __restrict__ sel_e,
                                                     float* __restrict__ sel_w,
                                                     float* __restrict__ part) {
  __shared__ float s_cnt[NE], s_ps[NE];
  int tid = threadIdx.x;
  if (tid < NE) { s_cnt[tid] = 0.f; s_ps[tid] = 0.f; }
  __syncthreads();
  int wave = tid >> 6, lane = tid & 63;
  float myc[NE], myp[NE];
  #pragma unroll
  for (int e = 0; e < NE; e++) { myc[e] = 0.f; myp[e] = 0.f; }

  for (int i = 0; i < 8; i++) {
    int token = blockIdx.x * 32 + wave * 8 + i;
    const float* xt = x + (size_t)token * DM;
    float acc[NE];
    #pragma unroll
    for (int e = 0; e < NE; e++) acc[e] = 0.f;
    #pragma unroll
    for (int kk = 0; kk < DM / 64; kk++) {
      int k = kk * 64 + lane;
      float xv = xt[k];
      f32x4 r0 = *(const f32x4*)(rw + k * NE);
      f32x4 r1 = *(const f32x4*)(rw + k * NE + 4);
      acc[0] += xv * r0[0]; acc[1] += xv * r0[1]; acc[2] += xv * r0[2]; acc[3] += xv * r0[3];
      acc[4] += xv * r1[0]; acc[5] += xv * r1[1]; acc[6] += xv * r1[2]; acc[7] += xv * r1[3];
    }
    #pragma unroll
    for (int off = 32; off >= 1; off >>= 1) {
      #pragma unroll
      for (int e = 0; e < NE; e++) acc[e] += __shfl_xor(acc[e], off, 64);
    }
    float mx = acc[0];
    #pragma unroll
    for (int e = 1; e < NE; e++) mx = fmaxf(mx, acc[e]);
    float p[NE]; float sum = 0.f;
    #pragma unroll
    for (int e = 0; e < NE; e++) { p[e] = expf(acc[e] - mx); sum += p[e]; }
    float inv = 1.f / sum;
    #pragma unroll
    for (int e = 0; e < NE; e++) p[e] *= inv;
    float sp[4]; int si[4]; unsigned used = 0;
    #pragma unroll
    for (int s = 0; s < 4; s++) {
      float bp = -1.f; int bi = 0;
      #pragma unroll
      for (int e = 0; e < NE; e++)
        if (!((used >> e) & 1u) && p[e] > bp) { bp = p[e]; bi = e; }
      used |= 1u << bi; sp[s] = bp; si[s] = bi;
    }
    float csum = 0.f, wsum = 0.f; bool keep[4];
    #pragma unroll
    for (int s = 0; s < 4; s++) {
      keep[s] = (s < 1) || (csum < 0.9f);
      csum += sp[s];
      if (keep[s]) wsum += sp[s];
    }
    wsum = fmaxf(wsum, 1e-9f);
    if (lane == 0) {
      #pragma unroll
      for (int s = 0; s < 4; s++) {
        sel_e[token * 4 + s] = keep[s] ? si[s] : -1;
        sel_w[token * 4 + s] = keep[s] ? sp[s] / wsum : 0.f;
      }
      #pragma unroll
      for (int e = 0; e < NE; e++) myp[e] += p[e];
      #pragma unroll
      for (int s = 0; s < 4; s++) if (keep[s]) myc[si[s]] += 1.f;
    }
  }
  if (lane == 0) {
    #pragma unroll
    for (int e = 0; e < NE; e++) { atomicAdd(&s_cnt[e], myc[e]); atomicAdd(&s_ps[e], myp[e]); }
  }
  __syncthreads();
  if (tid < NE) {
    part[blockIdx.x * 16 + tid] = s_cnt[tid];
    part[blockIdx.x * 16 + 8 + tid] = s_ps[tid];
  }
}

// ---------------- prep: aux scalar + expert bases (256-aligned) ----------------
__global__ void prep_kernel(const float* __restrict__ part, float* __restrict__ auxp,
                            int* __restrict__ meta) {
  __shared__ float red[16];
  int tid = threadIdx.x;
  if (tid < 16) {
    float s = 0.f;
    for (int b = 0; b < 256; b++) s += part[b * 16 + tid];
    red[tid] = s;
  }
  __syncthreads();
  if (tid == 0) {
    float tot = 0.f;
    for (int e = 0; e < NE; e++) tot += red[e];
    float t = fmaxf(tot, 1.f), s = 0.f;
    for (int e = 0; e < NE; e++) s += (red[e] / t) * (red[NE + e] / (float)NTOK);
    auxp[0] = 0.01f * (float)NE * s;
    int off = 0;
    for (int e = 0; e < NE; e++) {
      int c = (int)(red[e] + 0.5f);
      meta[e] = c; meta[8 + e] = off;
      off += (c + 255) & ~255;   // 256-granule padding (M-tile = 256)
    }
  }
  if (tid < NE) meta[16 + tid] = 0;
}

// ---------------- build compact assignment lists ----------------
__global__ __launch_bounds__(256) void build_kernel(const int* __restrict__ sel_e,
                                                    const float* __restrict__ sel_w,
                                                    int* __restrict__ meta,
                                                    int* __restrict__ mlist,
                                                    float* __restrict__ wrow,
                                                    int* __restrict__ arow) {
  __shared__ int lcnt[NE], roff[NE];
  int tid = threadIdx.x;
  if (tid < NE) lcnt[tid] = 0;
  __syncthreads();
  int t = blockIdx.x * 32 + tid;
  int slots[4], es[4];
  bool active = tid < 32;
  if (active) {
    #pragma unroll
    for (int s = 0; s < 4; s++) {
      es[s] = sel_e[t * 4 + s];
      slots[s] = (es[s] >= 0) ? atomicAdd(&lcnt[es[s]], 1) : -1;
    }
  }
  __syncthreads();
  if (tid < NE) roff[tid] = atomicAdd(&meta[16 + tid], lcnt[tid]);
  __syncthreads();
  if (active) {
    #pragma unroll
    for (int s = 0; s < 4; s++) {
      int e = es[s];
      if (e >= 0) {
        int hrow = meta[8 + e] + roff[e] + slots[s];
        mlist[hrow] = t;
        wrow[hrow] = sel_w[t * 4 + s];
        arow[t * 4 + s] = hrow;
      } else {
        arow[t * 4 + s] = -1;
      }
    }
  }
}

// ================= 256x256 8-phase GEMM machinery (geometry validated in R4) ==========
// LDS per matrix: 4 regions (buf 0/1 x half 0/1) of 16 KB: [128 rows][8 slots of 16B],
// phys slot = logical ^ (row&7); linear DMA dest + inverse-swizzled global source.
// 8 waves (2M x 4N); wave output 128x64. Phase (ks,Mh) reads A-half Mh; B-half is fixed
// per wave (wn>>1) and read EVERY phase -> B regions free only at ph4/ph8.
// B-frag reuse: bfr registers loaded at (ks,Mh0) are reused at (ks,Mh1) -> 24 ds_reads
// per K-tile per wave instead of 32.
// STAGGERED STAGING (the R4 fix): each region restaged the phase after it dies, giving
// every waited half a 3-4 phase (~900-1000 cy) lead:
//   ph1: A(t+1,h1), B(t+1,h0), B(t+1,h1)   [freed at ph8-prev]
//   ph4: A(t+2,h0)  + vmcnt(2) + barrier   [freed at ph3; wait covers tile t+1]
//   ph5: A(t+2,h1), B(t+2,h0), B(t+2,h1)   [freed at ph4]
//   ph8: A(t+3,h0)  + vmcnt(2) + barrier   [freed at ph7; wait covers tile t+2]
// Ledger (2 loads/half/wave): prologue 10 issues -> vmcnt(2). Steady ph4: in flight =
// ph8prev(2)+ph1(6)+ph4(2)=10, vmcnt(2) completes first 8 = tile t+1. ph8 symmetric.
// Final iter: ph4 vmcnt(0) drains the last 8; no stages beyond NT (guarded).

#define STAGE_A(TILE, HALF) do { if ((TILE) < NT_) { \
    short* d_ = As + (((TILE) & 1) * 2 + (HALF)) * 8192 + wave * 512; \
    GLD_LDS16(apt[HALF][0] + (TILE) * 64, d_); \
    GLD_LDS16(apt[HALF][1] + (TILE) * 64, d_ + 4096); } } while (0)

#define STAGE_B(TILE, HALF) do { if ((TILE) < NT_) { \
    short* d_ = Bs + (((TILE) & 1) * 2 + (HALF)) * 8192 + wave * 512; \
    GLD_LDS16(bpt[HALF][0] + (TILE) * 64, d_); \
    GLD_LDS16(bpt[HALF][1] + (TILE) * 64, d_ + 4096); } } while (0)

// LOADB/WAITN are compile-time constants. STG (variadic) = staging ops for this phase.
#define PH(BUF, KS, MH, LOADB, WAITN, ...) do { \
    unsigned ab_ = ldsA + (BUF) * 32768u + soB[KS]; \
    bfrag afr[4]; \
    afr[0] = lds_read_b128(ab_ + aRow[(MH) * 4 + 0]); \
    afr[1] = lds_read_b128(ab_ + aRow[(MH) * 4 + 1]); \
    afr[2] = lds_read_b128(ab_ + aRow[(MH) * 4 + 2]); \
    afr[3] = lds_read_b128(ab_ + aRow[(MH) * 4 + 3]); \
    if (LOADB) { \
      unsigned bb_ = ldsB + (BUF) * 32768u + soB[KS]; \
      bfr[0] = lds_read_b128(bb_ + bRow[0]); \
      bfr[1] = lds_read_b128(bb_ + bRow[1]); \
      bfr[2] = lds_read_b128(bb_ + bRow[2]); \
      bfr[3] = lds_read_b128(bb_ + bRow[3]); \
    } \
    __VA_ARGS__; \
    wg_barrier(); \
    asm volatile("s_waitcnt lgkmcnt(0)" ::: "memory"); \
    __builtin_amdgcn_sched_barrier(0); \
    __builtin_amdgcn_s_setprio(1); \
    _Pragma("unroll") \
    for (int q_ = 0; q_ < 4; q_++) \
      _Pragma("unroll") \
      for (int n_ = 0; n_ < 4; n_++) \
        acc[(MH) * 4 + q_][n_] = __builtin_amdgcn_mfma_f32_16x16x32_bf16( \
            afr[q_], bfr[n_], acc[(MH) * 4 + q_][n_], 0, 0, 0); \
    __builtin_amdgcn_s_setprio(0); \
    if ((WAITN) == 2) { asm volatile("s_waitcnt vmcnt(2)" ::: "memory"); } \
    else if ((WAITN) == 0) { asm volatile("s_waitcnt vmcnt(0)" ::: "memory"); } \
    wg_barrier(); \
  } while (0)

#define KLOOP_PROLOGUE() do { \
    STAGE_A(0, 0); STAGE_A(0, 1); STAGE_B(0, 0); STAGE_B(0, 1); STAGE_A(1, 0); \
    asm volatile("s_waitcnt vmcnt(2)" ::: "memory"); \
    wg_barrier(); \
  } while (0)

#define KLOOP_STEADY(t0) do { \
    PH(0, 0, 0, 1, -1, STAGE_A((t0) + 1, 1); STAGE_B((t0) + 1, 0); STAGE_B((t0) + 1, 1)); \
    PH(0, 0, 1, 0, -1, ((void)0)); \
    PH(0, 1, 0, 1, -1, ((void)0)); \
    PH(0, 1, 1, 0,  2, STAGE_A((t0) + 2, 0)); \
    PH(1, 0, 0, 1, -1, STAGE_A((t0) + 2, 1); STAGE_B((t0) + 2, 0); STAGE_B((t0) + 2, 1)); \
    PH(1, 0, 1, 0, -1, ((void)0)); \
    PH(1, 1, 0, 1, -1, ((void)0)); \
    PH(1, 1, 1, 0,  2, STAGE_A((t0) + 3, 0)); \
  } while (0)

#define KLOOP_FINAL(t0) do { \
    PH(0, 0, 0, 1, -1, STAGE_A((t0) + 1, 1); STAGE_B((t0) + 1, 0); STAGE_B((t0) + 1, 1)); \
    PH(0, 0, 1, 0, -1, ((void)0)); \
    PH(0, 1, 0, 1, -1, ((void)0)); \
    PH(0, 1, 1, 0,  0, ((void)0)); \
    PH(1, 0, 0, 1, -1, ((void)0)); \
    PH(1, 0, 1, 0, -1, ((void)0)); \
    PH(1, 1, 0, 1, -1, ((void)0)); \
    PH(1, 1, 1, 0, -1, ((void)0)); \
  } while (0)

// ---------------- sparse GEMM1: H = gelu(A @ W1 + b1), 256x256 tile ----------------
__global__ __launch_bounds__(512, 2) void gemm1_sp(const short* __restrict__ A,
                                                   const short* __restrict__ W1t,
                                                   const float* __restrict__ b1,
                                                   short* __restrict__ H,
                                                   const int* __restrict__ mlist,
                                                   const int* __restrict__ meta) {
  __shared__ __align__(16) short As[2 * 2 * 128 * 64];   // 64 KB
  __shared__ __align__(16) short Bs[2 * 2 * 128 * 64];   // 64 KB
  constexpr int NT_ = DM / 64;       // 8 K-tiles
  constexpr int NITER = NT_ / 2;     // 4
  int e = blockIdx.x >> 5, j = blockIdx.x & 31;
  int cnt = meta[e];
  if (j * 256 >= cnt) return;
  int base = meta[8 + e];
  int tid = threadIdx.x, wave = tid >> 6, lane = tid & 63;
  int wm = wave >> 2, wn = wave & 3, quad = lane >> 4, l16 = lane & 15;
  int n0 = blockIdx.y * 256;
  const short* Bt = W1t + (size_t)e * DFF * DM;

  // staging source pointers: call k covers row k*64 + (tid>>3) of each 128-row half
  int srow = tid >> 3;
  int scol = ((tid & 7) ^ (srow & 7)) * 8;
  const short* apt[2][2]; const short* bpt[2][2];
  #pragma unroll
  for (int h = 0; h < 2; h++)
    #pragma unroll
    for (int k = 0; k < 2; k++) {
      int rl = j * 256 + h * 128 + k * 64 + srow;
      int tok = mlist[base + (rl < cnt ? rl : cnt - 1)];
      apt[h][k] = A + (size_t)tok * DM + scol;
      bpt[h][k] = Bt + (size_t)(n0 + h * 128 + k * 64 + srow) * DM + scol;
    }

  // ds_read addresses (bytes): region = buf*32768 + half*16384; row stride 128 B
  unsigned ldsA = LDS_OFF(As), ldsB = LDS_OFF(Bs);
  unsigned aRow[8], bRow[4], soB[2];
  #pragma unroll
  for (int mi = 0; mi < 8; mi++)
    aRow[mi] = (unsigned)((mi >> 2) * 16384 + ((mi & 3) * 32 + wm * 16 + l16) * 128);
  #pragma unroll
  for (int ni = 0; ni < 4; ni++)
    bRow[ni] = (unsigned)((wn >> 1) * 16384 + ((wn & 1) * 64 + ni * 16 + l16) * 128);
  #pragma unroll
  for (int ks = 0; ks < 2; ks++)
    soB[ks] = (unsigned)((((ks << 2) | quad) ^ (l16 & 7)) << 4);

  f32x4 acc[8][4];
  #pragma unroll
  for (int i = 0; i < 8; i++)
    #pragma unroll
    for (int jj = 0; jj < 4; jj++) acc[i][jj] = (f32x4){0.f, 0.f, 0.f, 0.f};
  bfrag bfr[4];

  KLOOP_PROLOGUE();
  #pragma unroll 1
  for (int i = 0; i < NITER - 1; ++i) KLOOP_STEADY(2 * i);
  KLOOP_FINAL(NT_ - 2);

  const float* bb = b1 + (size_t)e * DFF;
  #pragma unroll
  for (int mi = 0; mi < 8; mi++) {
    int rbase = base + j * 256 + mi * 32 + wm * 16 + quad * 4;
    #pragma unroll
    for (int ni = 0; ni < 4; ni++) {
      int col = n0 + wn * 64 + ni * 16 + l16;
      float bv = bb[col];
      #pragma unroll
      for (int r = 0; r < 4; r++)
        H[(size_t)(rbase + r) * DFF + col] = f2bf(fast_gelu(acc[mi][ni][r] + bv));
    }
  }
}

// ---------------- sparse GEMM2: partial = w * (H @ W2 + b2), 256x256 tile ----------------
__global__ __launch_bounds__(512, 2) void gemm2_sp(const short* __restrict__ H,
                                                   const short* __restrict__ W2t,
                                                   const float* __restrict__ b2,
                                                   short* __restrict__ partial,
                                                   const float* __restrict__ wrow,
                                                   const int* __restrict__ meta) {
  __shared__ __align__(16) short As[2 * 2 * 128 * 64];
  __shared__ __align__(16) short Bs[2 * 2 * 128 * 64];
  constexpr int NT_ = DFF / 64;      // 32 K-tiles
  constexpr int NITER = NT_ / 2;     // 16
  int e = blockIdx.x >> 5, j = blockIdx.x & 31;
  int cnt = meta[e];
  if (j * 256 >= cnt) return;
  int base = meta[8 + e];
  int tid = threadIdx.x, wave = tid >> 6, lane = tid & 63;
  int wm = wave >> 2, wn = wave & 3, quad = lane >> 4, l16 = lane & 15;
  int n0 = blockIdx.y * 256;
  const short* Bt = W2t + (size_t)e * DM * DFF;

  int srow = tid >> 3;
  int scol = ((tid & 7) ^ (srow & 7)) * 8;
  const short* apt[2][2]; const short* bpt[2][2];
  #pragma unroll
  for (int h = 0; h < 2; h++)
    #pragma unroll
    for (int k = 0; k < 2; k++) {
      int rl = j * 256 + h * 128 + k * 64 + srow;
      apt[h][k] = H + (size_t)(base + rl) * DFF + scol;
      bpt[h][k] = Bt + (size_t)(n0 + h * 128 + k * 64 + srow) * DFF + scol;
    }

  unsigned ldsA = LDS_OFF(As), ldsB = LDS_OFF(Bs);
  unsigned aRow[8], bRow[4], soB[2];
  #pragma unroll
  for (int mi = 0; mi < 8; mi++)
    aRow[mi] = (unsigned)((mi >> 2) * 16384 + ((mi & 3) * 32 + wm * 16 + l16) * 128);
  #pragma unroll
  for (int ni = 0; ni < 4; ni++)
    bRow[ni] = (unsigned)((wn >> 1) * 16384 + ((wn & 1) * 64 + ni * 16 + l16) * 128);
  #pragma unroll
  for (int ks = 0; ks < 2; ks++)
    soB[ks] = (unsigned)((((ks << 2) | quad) ^ (l16 & 7)) << 4);

  f32x4 acc[8][4];
  #pragma unroll
  for (int i = 0; i < 8; i++)
    #pragma unroll
    for (int jj = 0; jj < 4; jj++) acc[i][jj] = (f32x4){0.f, 0.f, 0.f, 0.f};
  bfrag bfr[4];

  KLOOP_PROLOGUE();
  #pragma unroll 1
  for (int i = 0; i < NITER - 1; ++i) KLOOP_STEADY(2 * i);
  KLOOP_FINAL(NT_ - 2);

  const float* bb = b2 + (size_t)e * DM;
  #pragma unroll
  for (int mi = 0; mi < 8; mi++) {
    int rbase = base + j * 256 + mi * 32 + wm * 16 + quad * 4;
    #pragma unroll
    for (int ni = 0; ni < 4; ni++) {
      int col = n0 + wn * 64 + ni * 16 + l16;
      float bv = bb[col];
      #pragma unroll
      for (int r = 0; r < 4; r++) {
        float w = wrow[rbase + r];
        partial[(size_t)(rbase + r) * DM + col] = f2bf(w * (acc[mi][ni][r] + bv));
      }
    }
  }
}

// ---------------- combine ----------------
__global__ __launch_bounds__(256) void combine_kernel(const short* __restrict__ partial,
                                                      const int* __restrict__ arow,
                                                      float* __restrict__ out) {
  int gid = blockIdx.x * 256 + threadIdx.x;
  int t = gid >> 6, c0 = (gid & 63) << 3;
  const int* ar = arow + t * 4;
  float o[8];
  #pragma unroll
  for (int k = 0; k < 8; k++) o[k] = 0.f;
  #pragma unroll
  for (int s = 0; s < 4; s++) {
    int a = ar[s];
    if (a >= 0) {
      union { u32x4 v; short s16[8]; } buf;
      buf.v = *(const u32x4*)(partial + (size_t)a * DM + c0);
      #pragma unroll
      for (int k = 0; k < 8; k++) o[k] += bf2f(buf.s16[k]);
    }
  }
  float* op = out + (size_t)t * DM + c0;
  *(f32x4*)op = (f32x4){o[0], o[1], o[2], o[3]};
  *(f32x4*)(op + 4) = (f32x4){o[4], o[5], o[6], o[7]};
}

extern "C" void kernel_launch(void* const* d_in, const int* in_sizes, int n_in,
                              void* d_out, int out_size, void* d_ws, size_t ws_size,
                              hipStream_t stream) {
  const float* x  = (const float*)d_in[0];
  const float* rw = (const float*)d_in[1];
  const float* W1 = (const float*)d_in[2];
  const float* b1 = (const float*)d_in[3];
  const float* W2 = (const float*)d_in[4];
  const float* b2 = (const float*)d_in[5];
  float* out = (float*)d_out;

  char* base_p = (char*)d_ws; char* p = base_p;
  auto carve = [&](size_t bytes) { char* r = p; p += (bytes + 255) & ~(size_t)255; return r; };
  short* xb    = (short*)carve((size_t)NTOK * DM * 2);
  short* w1b   = (short*)carve((size_t)NE * DM * DFF * 2);  // [e][DFF][DM]
  short* w2b   = (short*)carve((size_t)NE * DFF * DM * 2);  // [e][DM][DFF]
  int*   sel_e = (int*)carve((size_t)NTOK * 4 * 4);
  float* sel_w = (float*)carve((size_t)NTOK * 4 * 4);
  float* part  = (float*)carve(256 * 16 * 4);
  int*   meta  = (int*)carve(64 * 4);
  int*   arow  = (int*)carve((size_t)NTOK * 4 * 4);
  int*   mlist = (int*)carve((size_t)ROWCAP * 4);
  float* wrow  = (float*)carve((size_t)ROWCAP * 4);
  short* Hbig  = (short*)carve((size_t)ROWCAP * DFF * 2);
  short* partial = (short*)carve((size_t)ROWCAP * DM * 2);

  cvt_kernel<<<(NTOK * DM / 4 + 255) / 256, 256, 0, stream>>>(x, xb, NTOK * DM / 4);
  cvtT_kernel<<<dim3(DM / 32, DFF / 32, NE), 256, 0, stream>>>(W1, w1b, DM, DFF);
  cvtT_kernel<<<dim3(DFF / 32, DM / 32, NE), 256, 0, stream>>>(W2, w2b, DFF, DM);
  router_kernel<<<256, 256, 0, stream>>>(x, rw, sel_e, sel_w, part);
  prep_kernel<<<1, 64, 0, stream>>>(part, out + (size_t)NTOK * DM, meta);
  build_kernel<<<256, 256, 0, stream>>>(sel_e, sel_w, meta, mlist, wrow, arow);
  gemm1_sp<<<dim3(NE * 32, DFF / 256), 512, 0, stream>>>(xb, w1b, b1, Hbig, mlist, meta);
  gemm2_sp<<<dim3(NE * 32, DM / 256), 512, 0, stream>>>(Hbig, w2b, b2, partial, wrow, meta);
  combine_kernel<<<NTOK * DM / 8 / 256, 256, 0, stream>>>(partial, arow, out);
}

// Round 7
// 429.416 us; speedup vs baseline: 1.0986x; 1.0986x over previous
//
#include <hip/hip_runtime.h>
#include <hip/hip_bf16.h>
#include <math.h>

#define NTOK 8192
#define DM 512
#define DFF 2048
#define NE 8
#define ROWCAP 33792   // 32768 assignments max + 8*128 granule padding

typedef __attribute__((ext_vector_type(8))) short bfrag;
typedef __attribute__((ext_vector_type(4))) float f32x4;
typedef __attribute__((ext_vector_type(4))) unsigned int u32x4;
typedef __attribute__((ext_vector_type(4))) short s16x4;

// async global->LDS, 16B/lane; LDS dest = wave-uniform base + lane*16 (global addr may be per-lane)
#define GLD_LDS16(gp, lp) __builtin_amdgcn_global_load_lds( \
    (const __attribute__((address_space(1))) void*)(gp),    \
    (__attribute__((address_space(3))) void*)(lp), 16, 0, 0)

// LDS byte offset of a generic pointer known to point into LDS
#define LDS_OFF(p) ((unsigned)(size_t)(__attribute__((address_space(3))) void*)(p))

// raw workgroup barrier WITHOUT the implicit s_waitcnt vmcnt(0) that __syncthreads carries.
__device__ __forceinline__ void wg_barrier() {
  asm volatile("" ::: "memory");
  __builtin_amdgcn_sched_barrier(0);
  __builtin_amdgcn_s_barrier();
  __builtin_amdgcn_sched_barrier(0);
  asm volatile("" ::: "memory");
}

// inline-asm ds_read_b128 with compile-time literal offset: invisible to the compiler's
// waitcnt pass (no implicit vmcnt(0) drain vs pending global_load_lds DMA), and the
// literal offset removes per-read VALU address adds.
// Caller MUST fence with s_waitcnt lgkmcnt(0) + sched_barrier(0) before consuming.
#define LDS_READ_OFF(dst, base, LIT) \
  asm volatile("ds_read_b128 %0, %1 offset:" LIT : "=v"(dst) : "v"(base))

__device__ __forceinline__ short f2bf(float f) {
  unsigned u = __builtin_bit_cast(unsigned, f);
  u += 0x7fffu + ((u >> 16) & 1u);
  return (short)(u >> 16);
}
__device__ __forceinline__ float bf2f(short s) {
  unsigned u = ((unsigned)(unsigned short)s) << 16;
  return __builtin_bit_cast(float, u);
}
// tanh-form GELU via hw exp2+rcp (~7 ops). max |diff vs erf-gelu| ~5e-4.
__device__ __forceinline__ float fast_gelu(float v) {
  float u = fmaf(v * v * v, 0.044715f, v) * 0.7978845608f;
  float ex = __builtin_amdgcn_exp2f(u * -2.8853900818f);
  return v * __builtin_amdgcn_rcpf(1.f + ex);
}

// ---------------- fp32 -> bf16 transpose-convert (vectorized short4 stores) ----------------
__global__ __launch_bounds__(256) void cvtT_kernel(const float* __restrict__ in,
                                                   short* __restrict__ o, int R, int C) {
  __shared__ float t[32][33];
  size_t eoff = (size_t)blockIdx.z * R * C;
  in += eoff; o += eoff;
  int r0 = blockIdx.x * 32, c0 = blockIdx.y * 32;
  int tx = threadIdx.x & 31, ty = threadIdx.x >> 5;
  #pragma unroll
  for (int i = 0; i < 32; i += 8)
    t[ty + i][tx] = in[(size_t)(r0 + ty + i) * C + c0 + tx];
  __syncthreads();
  // store side: thread = (tx4 in 0..7) x (oc in 0..31); one short4 (8B) per thread
  int tx4 = threadIdx.x & 7, oc = threadIdx.x >> 3;
  s16x4 v;
  #pragma unroll
  for (int jj = 0; jj < 4; jj++) v[jj] = f2bf(t[tx4 * 4 + jj][oc]);
  *(s16x4*)(o + (size_t)(c0 + oc) * R + r0 + tx4 * 4) = v;
}

// ---------------- router (fused: also emits xb = bf16(x)) ----------------
__global__ __launch_bounds__(256) void router_kernel(const float* __restrict__ x,
                                                     const float* __restrict__ rw,
                                                     short* __restrict__ xb,
                                                     int* __restrict__ sel_e,
                                                     float* __restrict__ sel_w,
                                                     float* __restrict__ part) {
  __shared__ float s_cnt[NE], s_ps[NE];
  int tid = threadIdx.x;
  if (tid < NE) { s_cnt[tid] = 0.f; s_ps[tid] = 0.f; }
  __syncthreads();
  int wave = tid >> 6, lane = tid & 63;
  float myc[NE], myp[NE];
  #pragma unroll
  for (int e = 0; e < NE; e++) { myc[e] = 0.f; myp[e] = 0.f; }

  for (int i = 0; i < 8; i++) {
    int token = blockIdx.x * 32 + wave * 8 + i;
    const float* xt = x + (size_t)token * DM;
    float acc[NE];
    #pragma unroll
    for (int e = 0; e < NE; e++) acc[e] = 0.f;
    #pragma unroll
    for (int kk = 0; kk < DM / 64; kk++) {
      int k = kk * 64 + lane;
      float xv = xt[k];
      xb[(size_t)token * DM + k] = f2bf(xv);   // fused fp32->bf16 emit
      f32x4 r0 = *(const f32x4*)(rw + k * NE);
      f32x4 r1 = *(const f32x4*)(rw + k * NE + 4);
      acc[0] += xv * r0[0]; acc[1] += xv * r0[1]; acc[2] += xv * r0[2]; acc[3] += xv * r0[3];
      acc[4] += xv * r1[0]; acc[5] += xv * r1[1]; acc[6] += xv * r1[2]; acc[7] += xv * r1[3];
    }
    #pragma unroll
    for (int off = 32; off >= 1; off >>= 1) {
      #pragma unroll
      for (int e = 0; e < NE; e++) acc[e] += __shfl_xor(acc[e], off, 64);
    }
    float mx = acc[0];
    #pragma unroll
    for (int e = 1; e < NE; e++) mx = fmaxf(mx, acc[e]);
    float p[NE]; float sum = 0.f;
    #pragma unroll
    for (int e = 0; e < NE; e++) { p[e] = expf(acc[e] - mx); sum += p[e]; }
    float inv = 1.f / sum;
    #pragma unroll
    for (int e = 0; e < NE; e++) p[e] *= inv;
    float sp[4]; int si[4]; unsigned used = 0;
    #pragma unroll
    for (int s = 0; s < 4; s++) {
      float bp = -1.f; int bi = 0;
      #pragma unroll
      for (int e = 0; e < NE; e++)
        if (!((used >> e) & 1u) && p[e] > bp) { bp = p[e]; bi = e; }
      used |= 1u << bi; sp[s] = bp; si[s] = bi;
    }
    float csum = 0.f, wsum = 0.f; bool keep[4];
    #pragma unroll
    for (int s = 0; s < 4; s++) {
      keep[s] = (s < 1) || (csum < 0.9f);
      csum += sp[s];
      if (keep[s]) wsum += sp[s];
    }
    wsum = fmaxf(wsum, 1e-9f);
    if (lane == 0) {
      #pragma unroll
      for (int s = 0; s < 4; s++) {
        sel_e[token * 4 + s] = keep[s] ? si[s] : -1;
        sel_w[token * 4 + s] = keep[s] ? sp[s] / wsum : 0.f;
      }
      #pragma unroll
      for (int e = 0; e < NE; e++) myp[e] += p[e];
      #pragma unroll
      for (int s = 0; s < 4; s++) if (keep[s]) myc[si[s]] += 1.f;
    }
  }
  if (lane == 0) {
    #pragma unroll
    for (int e = 0; e < NE; e++) { atomicAdd(&s_cnt[e], myc[e]); atomicAdd(&s_ps[e], myp[e]); }
  }
  __syncthreads();
  if (tid < NE) {
    part[blockIdx.x * 16 + tid] = s_cnt[tid];
    part[blockIdx.x * 16 + 8 + tid] = s_ps[tid];
  }
}

// ---------------- prep: aux scalar + expert bases (128-aligned), parallel reduce ----------------
__global__ __launch_bounds__(256) void prep_kernel(const float* __restrict__ part,
                                                   float* __restrict__ auxp,
                                                   int* __restrict__ meta) {
  __shared__ float red2[16][16];   // [group][idx]
  __shared__ float red[16];
  int tid = threadIdx.x;
  int idx = tid & 15, g = tid >> 4;      // 16 groups, each sums 16 router blocks
  float s = 0.f;
  #pragma unroll
  for (int b = 0; b < 16; b++) s += part[(g * 16 + b) * 16 + idx];
  red2[g][idx] = s;
  __syncthreads();
  if (tid < 16) {
    float t = 0.f;
    #pragma unroll
    for (int g2 = 0; g2 < 16; g2++) t += red2[g2][tid];
    red[tid] = t;
  }
  __syncthreads();
  if (tid == 0) {
    float tot = 0.f;
    for (int e = 0; e < NE; e++) tot += red[e];
    float t = fmaxf(tot, 1.f), s2 = 0.f;
    for (int e = 0; e < NE; e++) s2 += (red[e] / t) * (red[NE + e] / (float)NTOK);
    auxp[0] = 0.01f * (float)NE * s2;
    int off = 0;
    for (int e = 0; e < NE; e++) {
      int c = (int)(red[e] + 0.5f);
      meta[e] = c; meta[8 + e] = off;
      off += (c + 127) & ~127;   // 128-granule padding (M-tile = 128)
    }
  }
  if (tid < NE) meta[16 + tid] = 0;
}

// ---------------- build compact assignment lists ----------------
__global__ __launch_bounds__(256) void build_kernel(const int* __restrict__ sel_e,
                                                    const float* __restrict__ sel_w,
                                                    int* __restrict__ meta,
                                                    int* __restrict__ mlist,
                                                    float* __restrict__ wrow,
                                                    int* __restrict__ arow) {
  __shared__ int lcnt[NE], roff[NE];
  int tid = threadIdx.x;
  if (tid < NE) lcnt[tid] = 0;
  __syncthreads();
  int t = blockIdx.x * 32 + tid;
  int slots[4], es[4];
  bool active = tid < 32;
  if (active) {
    #pragma unroll
    for (int s = 0; s < 4; s++) {
      es[s] = sel_e[t * 4 + s];
      slots[s] = (es[s] >= 0) ? atomicAdd(&lcnt[es[s]], 1) : -1;
    }
  }
  __syncthreads();
  if (tid < NE) roff[tid] = atomicAdd(&meta[16 + tid], lcnt[tid]);
  __syncthreads();
  if (active) {
    #pragma unroll
    for (int s = 0; s < 4; s++) {
      int e = es[s];
      if (e >= 0) {
        int hrow = meta[8 + e] + roff[e] + slots[s];
        mlist[hrow] = t;
        wrow[hrow] = sel_w[t * 4 + s];
        arow[t * 4 + s] = hrow;
      } else {
        arow[t * 4 + s] = -1;
      }
    }
  }
}

// ---------------- sparse GEMM1, 128x128 tile, BK=64, counted-vmcnt + asm ds_read ----------------
// R2-verified structure (133.8 us). LDS: [128 rows][8 slots of 16B] per buffer, phys slot =
// logical ^ (row&7) (both-sides swizzle: linear DMA dest + inverse-swizzled global source +
// swizzled asm read). vmcnt(8) at loop top is a TRUE wait: up to 16 loads outstanding
// (tiles t, t+1); VMEM completion is FIFO per wave, so vmcnt(8) completes the oldest 8 =
// tile t. Per-phase base + literal offsets {0,2048,4096,6144} cut VALU address adds.
__global__ __launch_bounds__(256, 2) void gemm1_sp(const short* __restrict__ A,
                                                   const short* __restrict__ W1t,
                                                   const float* __restrict__ b1,
                                                   short* __restrict__ H,
                                                   const int* __restrict__ mlist,
                                                   const int* __restrict__ meta) {
  __shared__ __align__(16) short As[2 * 128 * 64];
  __shared__ __align__(16) short Bs[2 * 128 * 64];
  int e = blockIdx.x >> 6, j = blockIdx.x & 63;
  int cnt = meta[e];
  if (j * 128 >= cnt) return;
  int base = meta[8 + e];
  int tid = threadIdx.x, wave = tid >> 6, lane = tid & 63;
  int wm = wave >> 1, wn = wave & 1, quad = lane >> 4, l16 = lane & 15;
  int n0 = blockIdx.y * 128;
  const short* Bt = W1t + (size_t)e * DFF * DM;

  // staging: chunk c = q*256 + tid; row r = c>>3; logical slot s = (c&7)^(r&7) at source
  const short* agp[4]; const short* bgp[4];
  #pragma unroll
  for (int q = 0; q < 4; q++) {
    int c = q * 256 + tid;
    int r = c >> 3, s = (c & 7) ^ (r & 7);
    int rl = j * 128 + r;
    int tok = mlist[base + (rl < cnt ? rl : cnt - 1)];
    agp[q] = A + (size_t)tok * DM + s * 8;
    bgp[q] = Bt + (size_t)(n0 + r) * DM + s * 8;
  }

  f32x4 acc[4][4];
  #pragma unroll
  for (int i = 0; i < 4; i++)
    #pragma unroll
    for (int jj = 0; jj < 4; jj++) acc[i][jj] = (f32x4){0.f, 0.f, 0.f, 0.f};

  auto stage = [&](int bsel, int kt) {
    short* Ab = As + bsel * 8192 + wave * 512;
    short* Bb = Bs + bsel * 8192 + wave * 512;
    #pragma unroll
    for (int q = 0; q < 4; q++) {
      GLD_LDS16(agp[q] + kt, Ab + q * 2048);
      GLD_LDS16(bgp[q] + kt, Bb + q * 2048);
    }
  };

  stage(0, 0);
  stage(1, 64);

  // per-thread read bases (row stride 128 B); fragment rows differ by literal 2048 B
  unsigned aAddr0 = LDS_OFF(As) + (wm * 64 + l16) * 128;
  unsigned bAddr0 = LDS_OFF(Bs) + (wn * 64 + l16) * 128;
  unsigned soB[2];
  #pragma unroll
  for (int ks = 0; ks < 2; ks++) soB[ks] = (unsigned)((((ks << 2) | quad) ^ (l16 & 7)) << 4);

  const int NT = DM / 64;   // 8
  for (int t = 0; t < NT; t++) {
    if (t + 1 < NT) asm volatile("s_waitcnt vmcnt(8)" ::: "memory");
    else            asm volatile("s_waitcnt vmcnt(0)" ::: "memory");
    wg_barrier();              // tile t visible to all waves
    unsigned bo = (unsigned)((t & 1) * 16384);
    #pragma unroll
    for (int ks = 0; ks < 2; ks++) {
      unsigned aB = aAddr0 + bo + soB[ks];
      unsigned bB = bAddr0 + bo + soB[ks];
      bfrag afr[4], bfr[4];
      LDS_READ_OFF(afr[0], aB, "0");    LDS_READ_OFF(afr[1], aB, "2048");
      LDS_READ_OFF(afr[2], aB, "4096"); LDS_READ_OFF(afr[3], aB, "6144");
      LDS_READ_OFF(bfr[0], bB, "0");    LDS_READ_OFF(bfr[1], bB, "2048");
      LDS_READ_OFF(bfr[2], bB, "4096"); LDS_READ_OFF(bfr[3], bB, "6144");
      asm volatile("s_waitcnt lgkmcnt(0)" ::: "memory");
      __builtin_amdgcn_sched_barrier(0);
      __builtin_amdgcn_s_setprio(1);
      #pragma unroll
      for (int mi = 0; mi < 4; mi++)
        #pragma unroll
        for (int ni = 0; ni < 4; ni++)
          acc[mi][ni] = __builtin_amdgcn_mfma_f32_16x16x32_bf16(afr[mi], bfr[ni], acc[mi][ni], 0, 0, 0);
      __builtin_amdgcn_s_setprio(0);
    }
    wg_barrier();              // all waves done reading buf[t&1]
    if (t + 2 < NT) stage(t & 1, (t + 2) * 64);   // overwrite just-vacated buffer
  }
  const float* bb = b1 + (size_t)e * DFF;
  #pragma unroll
  for (int mi = 0; mi < 4; mi++) {
    int rbase = base + j * 128 + wm * 64 + mi * 16 + quad * 4;
    #pragma unroll
    for (int ni = 0; ni < 4; ni++) {
      int col = n0 + wn * 64 + ni * 16 + l16;
      float bv = bb[col];
      #pragma unroll
      for (int r = 0; r < 4; r++)
        H[(size_t)(rbase + r) * DFF + col] = f2bf(fast_gelu(acc[mi][ni][r] + bv));
    }
  }
}

// ---------------- sparse GEMM2, same structure, K=DFF ----------------
__global__ __launch_bounds__(256, 2) void gemm2_sp(const short* __restrict__ H,
                                                   const short* __restrict__ W2t,
                                                   const float* __restrict__ b2,
                                                   short* __restrict__ partial,
                                                   const float* __restrict__ wrow,
                                                   const int* __restrict__ meta) {
  __shared__ __align__(16) short As[2 * 128 * 64];
  __shared__ __align__(16) short Bs[2 * 128 * 64];
  int e = blockIdx.x >> 6, j = blockIdx.x & 63;
  int cnt = meta[e];
  if (j * 128 >= cnt) return;
  int base = meta[8 + e];
  int tid = threadIdx.x, wave = tid >> 6, lane = tid & 63;
  int wm = wave >> 1, wn = wave & 1, quad = lane >> 4, l16 = lane & 15;
  int n0 = blockIdx.y * 128;
  const short* Bt = W2t + (size_t)e * DM * DFF;

  const short* agp[4]; const short* bgp[4];
  #pragma unroll
  for (int q = 0; q < 4; q++) {
    int c = q * 256 + tid;
    int r = c >> 3, s = (c & 7) ^ (r & 7);
    agp[q] = H + (size_t)(base + j * 128 + r) * DFF + s * 8;
    bgp[q] = Bt + (size_t)(n0 + r) * DFF + s * 8;
  }

  f32x4 acc[4][4];
  #pragma unroll
  for (int i = 0; i < 4; i++)
    #pragma unroll
    for (int jj = 0; jj < 4; jj++) acc[i][jj] = (f32x4){0.f, 0.f, 0.f, 0.f};

  auto stage = [&](int bsel, int kt) {
    short* Ab = As + bsel * 8192 + wave * 512;
    short* Bb = Bs + bsel * 8192 + wave * 512;
    #pragma unroll
    for (int q = 0; q < 4; q++) {
      GLD_LDS16(agp[q] + kt, Ab + q * 2048);
      GLD_LDS16(bgp[q] + kt, Bb + q * 2048);
    }
  };

  stage(0, 0);
  stage(1, 64);

  unsigned aAddr0 = LDS_OFF(As) + (wm * 64 + l16) * 128;
  unsigned bAddr0 = LDS_OFF(Bs) + (wn * 64 + l16) * 128;
  unsigned soB[2];
  #pragma unroll
  for (int ks = 0; ks < 2; ks++) soB[ks] = (unsigned)((((ks << 2) | quad) ^ (l16 & 7)) << 4);

  const int NT = DFF / 64;  // 32
  for (int t = 0; t < NT; t++) {
    if (t + 1 < NT) asm volatile("s_waitcnt vmcnt(8)" ::: "memory");
    else            asm volatile("s_waitcnt vmcnt(0)" ::: "memory");
    wg_barrier();
    unsigned bo = (unsigned)((t & 1) * 16384);
    #pragma unroll
    for (int ks = 0; ks < 2; ks++) {
      unsigned aB = aAddr0 + bo + soB[ks];
      unsigned bB = bAddr0 + bo + soB[ks];
      bfrag afr[4], bfr[4];
      LDS_READ_OFF(afr[0], aB, "0");    LDS_READ_OFF(afr[1], aB, "2048");
      LDS_READ_OFF(afr[2], aB, "4096"); LDS_READ_OFF(afr[3], aB, "6144");
      LDS_READ_OFF(bfr[0], bB, "0");    LDS_READ_OFF(bfr[1], bB, "2048");
      LDS_READ_OFF(bfr[2], bB, "4096"); LDS_READ_OFF(bfr[3], bB, "6144");
      asm volatile("s_waitcnt lgkmcnt(0)" ::: "memory");
      __builtin_amdgcn_sched_barrier(0);
      __builtin_amdgcn_s_setprio(1);
      #pragma unroll
      for (int mi = 0; mi < 4; mi++)
        #pragma unroll
        for (int ni = 0; ni < 4; ni++)
          acc[mi][ni] = __builtin_amdgcn_mfma_f32_16x16x32_bf16(afr[mi], bfr[ni], acc[mi][ni], 0, 0, 0);
      __builtin_amdgcn_s_setprio(0);
    }
    wg_barrier();
    if (t + 2 < NT) stage(t & 1, (t + 2) * 64);
  }
  const float* bb = b2 + (size_t)e * DM;
  #pragma unroll
  for (int mi = 0; mi < 4; mi++) {
    int rbase = base + j * 128 + wm * 64 + mi * 16 + quad * 4;
    #pragma unroll
    for (int ni = 0; ni < 4; ni++) {
      int col = n0 + wn * 64 + ni * 16 + l16;
      float bv = bb[col];
      #pragma unroll
      for (int r = 0; r < 4; r++) {
        float w = wrow[rbase + r];
        partial[(size_t)(rbase + r) * DM + col] = f2bf(w * (acc[mi][ni][r] + bv));
      }
    }
  }
}

// ---------------- combine ----------------
__global__ __launch_bounds__(256) void combine_kernel(const short* __restrict__ partial,
                                                      const int* __restrict__ arow,
                                                      float* __restrict__ out) {
  int gid = blockIdx.x * 256 + threadIdx.x;
  int t = gid >> 6, c0 = (gid & 63) << 3;
  const int* ar = arow + t * 4;
  float o[8];
  #pragma unroll
  for (int k = 0; k < 8; k++) o[k] = 0.f;
  #pragma unroll
  for (int s = 0; s < 4; s++) {
    int a = ar[s];
    if (a >= 0) {
      union { u32x4 v; short s16[8]; } buf;
      buf.v = *(const u32x4*)(partial + (size_t)a * DM + c0);
      #pragma unroll
      for (int k = 0; k < 8; k++) o[k] += bf2f(buf.s16[k]);
    }
  }
  float* op = out + (size_t)t * DM + c0;
  *(f32x4*)op = (f32x4){o[0], o[1], o[2], o[3]};
  *(f32x4*)(op + 4) = (f32x4){o[4], o[5], o[6], o[7]};
}

extern "C" void kernel_launch(void* const* d_in, const int* in_sizes, int n_in,
                              void* d_out, int out_size, void* d_ws, size_t ws_size,
                              hipStream_t stream) {
  const float* x  = (const float*)d_in[0];
  const float* rw = (const float*)d_in[1];
  const float* W1 = (const float*)d_in[2];
  const float* b1 = (const float*)d_in[3];
  const float* W2 = (const float*)d_in[4];
  const float* b2 = (const float*)d_in[5];
  float* out = (float*)d_out;

  char* base_p = (char*)d_ws; char* p = base_p;
  auto carve = [&](size_t bytes) { char* r = p; p += (bytes + 255) & ~(size_t)255; return r; };
  short* xb    = (short*)carve((size_t)NTOK * DM * 2);
  short* w1b   = (short*)carve((size_t)NE * DM * DFF * 2);  // [e][DFF][DM]
  short* w2b   = (short*)carve((size_t)NE * DFF * DM * 2);  // [e][DM][DFF]
  int*   sel_e = (int*)carve((size_t)NTOK * 4 * 4);
  float* sel_w = (float*)carve((size_t)NTOK * 4 * 4);
  float* part  = (float*)carve(256 * 16 * 4);
  int*   meta  = (int*)carve(64 * 4);
  int*   arow  = (int*)carve((size_t)NTOK * 4 * 4);
  int*   mlist = (int*)carve((size_t)ROWCAP * 4);
  float* wrow  = (float*)carve((size_t)ROWCAP * 4);
  short* Hbig  = (short*)carve((size_t)ROWCAP * DFF * 2);
  short* partial = (short*)carve((size_t)ROWCAP * DM * 2);

  cvtT_kernel<<<dim3(DM / 32, DFF / 32, NE), 256, 0, stream>>>(W1, w1b, DM, DFF);
  cvtT_kernel<<<dim3(DFF / 32, DM / 32, NE), 256, 0, stream>>>(W2, w2b, DFF, DM);
  router_kernel<<<256, 256, 0, stream>>>(x, rw, xb, sel_e, sel_w, part);
  prep_kernel<<<1, 256, 0, stream>>>(part, out + (size_t)NTOK * DM, meta);
  build_kernel<<<256, 256, 0, stream>>>(sel_e, sel_w, meta, mlist, wrow, arow);
  gemm1_sp<<<dim3(NE * 64, DFF / 128), 256, 0, stream>>>(xb, w1b, b1, Hbig, mlist, meta);
  gemm2_sp<<<dim3(NE * 64, DM / 128), 256, 0, stream>>>(Hbig, w2b, b2, partial, wrow, meta);
  combine_kernel<<<NTOK * DM / 8 / 256, 256, 0, stream>>>(partial, arow, out);
}

// Round 8
// 382.855 us; speedup vs baseline: 1.2322x; 1.1216x over previous
//
#include <hip/hip_runtime.h>
#include <hip/hip_bf16.h>
#include <math.h>

#define NTOK 8192
#define DM 512
#define DFF 2048
#define NE 8
#define ROWCAP 33792   // 32768 assignments max + 8*128 granule padding

typedef __attribute__((ext_vector_type(8))) short bfrag;
typedef __attribute__((ext_vector_type(4))) float f32x4;
typedef __attribute__((ext_vector_type(4))) unsigned int u32x4;
typedef __attribute__((ext_vector_type(4))) short s16x4;

// async global->LDS, 16B/lane; LDS dest = wave-uniform base + lane*16 (global addr may be per-lane)
#define GLD_LDS16(gp, lp) __builtin_amdgcn_global_load_lds( \
    (const __attribute__((address_space(1))) void*)(gp),    \
    (__attribute__((address_space(3))) void*)(lp), 16, 0, 0)

// LDS byte offset of a generic pointer known to point into LDS
#define LDS_OFF(p) ((unsigned)(size_t)(__attribute__((address_space(3))) void*)(p))

// raw workgroup barrier WITHOUT the implicit s_waitcnt vmcnt(0) that __syncthreads carries.
__device__ __forceinline__ void wg_barrier() {
  asm volatile("" ::: "memory");
  __builtin_amdgcn_sched_barrier(0);
  __builtin_amdgcn_s_barrier();
  __builtin_amdgcn_sched_barrier(0);
  asm volatile("" ::: "memory");
}

// inline-asm ds_read_b128 with compile-time literal offset: invisible to the compiler's
// waitcnt pass (no implicit vmcnt(0) drain vs pending global_load_lds DMA), and the
// literal offset removes per-read VALU address adds.
// Caller MUST fence with s_waitcnt lgkmcnt(0) + sched_barrier(0) before consuming.
#define LDS_READ_OFF(dst, base, LIT) \
  asm volatile("ds_read_b128 %0, %1 offset:" LIT : "=v"(dst) : "v"(base))

__device__ __forceinline__ short f2bf(float f) {
  unsigned u = __builtin_bit_cast(unsigned, f);
  u += 0x7fffu + ((u >> 16) & 1u);
  return (short)(u >> 16);
}
__device__ __forceinline__ float bf2f(short s) {
  unsigned u = ((unsigned)(unsigned short)s) << 16;
  return __builtin_bit_cast(float, u);
}
// tanh-form GELU via hw exp2+rcp (~7 ops). max |diff vs erf-gelu| ~5e-4.
__device__ __forceinline__ float fast_gelu(float v) {
  float u = fmaf(v * v * v, 0.044715f, v) * 0.7978845608f;
  float ex = __builtin_amdgcn_exp2f(u * -2.8853900818f);
  return v * __builtin_amdgcn_rcpf(1.f + ex);
}

// ---------------- fp32 -> bf16 transpose-convert (vectorized short4 stores) ----------------
__global__ __launch_bounds__(256) void cvtT_kernel(const float* __restrict__ in,
                                                   short* __restrict__ o, int R, int C) {
  __shared__ float t[32][33];
  size_t eoff = (size_t)blockIdx.z * R * C;
  in += eoff; o += eoff;
  int r0 = blockIdx.x * 32, c0 = blockIdx.y * 32;
  int tx = threadIdx.x & 31, ty = threadIdx.x >> 5;
  #pragma unroll
  for (int i = 0; i < 32; i += 8)
    t[ty + i][tx] = in[(size_t)(r0 + ty + i) * C + c0 + tx];
  __syncthreads();
  // store side: thread = (tx4 in 0..7) x (oc in 0..31); one short4 (8B) per thread
  int tx4 = threadIdx.x & 7, oc = threadIdx.x >> 3;
  s16x4 v;
  #pragma unroll
  for (int jj = 0; jj < 4; jj++) v[jj] = f2bf(t[tx4 * 4 + jj][oc]);
  *(s16x4*)(o + (size_t)(c0 + oc) * R + r0 + tx4 * 4) = v;
}

// ---------------- router (fused: also emits xb = bf16(x)) ----------------
__global__ __launch_bounds__(256) void router_kernel(const float* __restrict__ x,
                                                     const float* __restrict__ rw,
                                                     short* __restrict__ xb,
                                                     int* __restrict__ sel_e,
                                                     float* __restrict__ sel_w,
                                                     float* __restrict__ part) {
  __shared__ float s_cnt[NE], s_ps[NE];
  int tid = threadIdx.x;
  if (tid < NE) { s_cnt[tid] = 0.f; s_ps[tid] = 0.f; }
  __syncthreads();
  int wave = tid >> 6, lane = tid & 63;
  float myc[NE], myp[NE];
  #pragma unroll
  for (int e = 0; e < NE; e++) { myc[e] = 0.f; myp[e] = 0.f; }

  for (int i = 0; i < 8; i++) {
    int token = blockIdx.x * 32 + wave * 8 + i;
    const float* xt = x + (size_t)token * DM;
    float acc[NE];
    #pragma unroll
    for (int e = 0; e < NE; e++) acc[e] = 0.f;
    #pragma unroll
    for (int kk = 0; kk < DM / 64; kk++) {
      int k = kk * 64 + lane;
      float xv = xt[k];
      xb[(size_t)token * DM + k] = f2bf(xv);   // fused fp32->bf16 emit
      f32x4 r0 = *(const f32x4*)(rw + k * NE);
      f32x4 r1 = *(const f32x4*)(rw + k * NE + 4);
      acc[0] += xv * r0[0]; acc[1] += xv * r0[1]; acc[2] += xv * r0[2]; acc[3] += xv * r0[3];
      acc[4] += xv * r1[0]; acc[5] += xv * r1[1]; acc[6] += xv * r1[2]; acc[7] += xv * r1[3];
    }
    #pragma unroll
    for (int off = 32; off >= 1; off >>= 1) {
      #pragma unroll
      for (int e = 0; e < NE; e++) acc[e] += __shfl_xor(acc[e], off, 64);
    }
    float mx = acc[0];
    #pragma unroll
    for (int e = 1; e < NE; e++) mx = fmaxf(mx, acc[e]);
    float p[NE]; float sum = 0.f;
    #pragma unroll
    for (int e = 0; e < NE; e++) { p[e] = expf(acc[e] - mx); sum += p[e]; }
    float inv = 1.f / sum;
    #pragma unroll
    for (int e = 0; e < NE; e++) p[e] *= inv;
    float sp[4]; int si[4]; unsigned used = 0;
    #pragma unroll
    for (int s = 0; s < 4; s++) {
      float bp = -1.f; int bi = 0;
      #pragma unroll
      for (int e = 0; e < NE; e++)
        if (!((used >> e) & 1u) && p[e] > bp) { bp = p[e]; bi = e; }
      used |= 1u << bi; sp[s] = bp; si[s] = bi;
    }
    float csum = 0.f, wsum = 0.f; bool keep[4];
    #pragma unroll
    for (int s = 0; s < 4; s++) {
      keep[s] = (s < 1) || (csum < 0.9f);
      csum += sp[s];
      if (keep[s]) wsum += sp[s];
    }
    wsum = fmaxf(wsum, 1e-9f);
    if (lane == 0) {
      #pragma unroll
      for (int s = 0; s < 4; s++) {
        sel_e[token * 4 + s] = keep[s] ? si[s] : -1;
        sel_w[token * 4 + s] = keep[s] ? sp[s] / wsum : 0.f;
      }
      #pragma unroll
      for (int e = 0; e < NE; e++) myp[e] += p[e];
      #pragma unroll
      for (int s = 0; s < 4; s++) if (keep[s]) myc[si[s]] += 1.f;
    }
  }
  if (lane == 0) {
    #pragma unroll
    for (int e = 0; e < NE; e++) { atomicAdd(&s_cnt[e], myc[e]); atomicAdd(&s_ps[e], myp[e]); }
  }
  __syncthreads();
  if (tid < NE) {
    part[blockIdx.x * 16 + tid] = s_cnt[tid];
    part[blockIdx.x * 16 + 8 + tid] = s_ps[tid];
  }
}

// ---------------- prep: aux scalar + expert bases (128-aligned), parallel reduce ----------------
__global__ __launch_bounds__(256) void prep_kernel(const float* __restrict__ part,
                                                   float* __restrict__ auxp,
                                                   int* __restrict__ meta) {
  __shared__ float red2[16][16];   // [group][idx]
  __shared__ float red[16];
  int tid = threadIdx.x;
  int idx = tid & 15, g = tid >> 4;      // 16 groups, each sums 16 router blocks
  float s = 0.f;
  #pragma unroll
  for (int b = 0; b < 16; b++) s += part[(g * 16 + b) * 16 + idx];
  red2[g][idx] = s;
  __syncthreads();
  if (tid < 16) {
    float t = 0.f;
    #pragma unroll
    for (int g2 = 0; g2 < 16; g2++) t += red2[g2][tid];
    red[tid] = t;
  }
  __syncthreads();
  if (tid == 0) {
    float tot = 0.f;
    for (int e = 0; e < NE; e++) tot += red[e];
    float t = fmaxf(tot, 1.f), s2 = 0.f;
    for (int e = 0; e < NE; e++) s2 += (red[e] / t) * (red[NE + e] / (float)NTOK);
    auxp[0] = 0.01f * (float)NE * s2;
    int off = 0;
    for (int e = 0; e < NE; e++) {
      int c = (int)(red[e] + 0.5f);
      meta[e] = c; meta[8 + e] = off;
      off += (c + 127) & ~127;   // 128-granule padding (M-tile = 128)
    }
  }
  if (tid < NE) meta[16 + tid] = 0;
}

// ---------------- build compact assignment lists ----------------
__global__ __launch_bounds__(256) void build_kernel(const int* __restrict__ sel_e,
                                                    const float* __restrict__ sel_w,
                                                    int* __restrict__ meta,
                                                    int* __restrict__ mlist,
                                                    float* __restrict__ wrow,
                                                    int* __restrict__ arow) {
  __shared__ int lcnt[NE], roff[NE];
  int tid = threadIdx.x;
  if (tid < NE) lcnt[tid] = 0;
  __syncthreads();
  int t = blockIdx.x * 32 + tid;
  int slots[4], es[4];
  bool active = tid < 32;
  if (active) {
    #pragma unroll
    for (int s = 0; s < 4; s++) {
      es[s] = sel_e[t * 4 + s];
      slots[s] = (es[s] >= 0) ? atomicAdd(&lcnt[es[s]], 1) : -1;
    }
  }
  __syncthreads();
  if (tid < NE) roff[tid] = atomicAdd(&meta[16 + tid], lcnt[tid]);
  __syncthreads();
  if (active) {
    #pragma unroll
    for (int s = 0; s < 4; s++) {
      int e = es[s];
      if (e >= 0) {
        int hrow = meta[8 + e] + roff[e] + slots[s];
        mlist[hrow] = t;
        wrow[hrow] = sel_w[t * 4 + s];
        arow[t * 4 + s] = hrow;
      } else {
        arow[t * 4 + s] = -1;
      }
    }
  }
}

// ---------------- sparse GEMM1, 128x128 tile, BK=64, counted-vmcnt + asm ds_read ----------------
// R2/R7-verified K-loop (132 us). NEW this round:
//  - grid swapped: blockIdx.x = N-tile (fast) so the 16 blocks sharing an A-tile are
//    consecutive dispatch IDs -> co-resident -> gathered A fetched from HBM once.
//  - epilogue stages the 128x128 output tile in LDS (Hs[128][136], 272B row stride,
//    16B-aligned) and emits coalesced dwordx4 stores (256B per 16 lanes) instead of
//    64 scalar 2B stores per thread.
__global__ __launch_bounds__(256, 2) void gemm1_sp(const short* __restrict__ A,
                                                   const short* __restrict__ W1t,
                                                   const float* __restrict__ b1,
                                                   short* __restrict__ H,
                                                   const int* __restrict__ mlist,
                                                   const int* __restrict__ meta) {
  __shared__ __align__(16) short smem[32768];   // 64 KB: As | Bs, reused as Hs in epilogue
  short* As = smem;
  short* Bs = smem + 16384;
  int e = blockIdx.y >> 6, j = blockIdx.y & 63;
  int cnt = meta[e];
  if (j * 128 >= cnt) return;
  int base = meta[8 + e];
  int tid = threadIdx.x, wave = tid >> 6, lane = tid & 63;
  int wm = wave >> 1, wn = wave & 1, quad = lane >> 4, l16 = lane & 15;
  int n0 = blockIdx.x * 128;
  const short* Bt = W1t + (size_t)e * DFF * DM;

  // staging: chunk c = q*256 + tid; row r = c>>3; logical slot s = (c&7)^(r&7) at source
  const short* agp[4]; const short* bgp[4];
  #pragma unroll
  for (int q = 0; q < 4; q++) {
    int c = q * 256 + tid;
    int r = c >> 3, s = (c & 7) ^ (r & 7);
    int rl = j * 128 + r;
    int tok = mlist[base + (rl < cnt ? rl : cnt - 1)];
    agp[q] = A + (size_t)tok * DM + s * 8;
    bgp[q] = Bt + (size_t)(n0 + r) * DM + s * 8;
  }

  f32x4 acc[4][4];
  #pragma unroll
  for (int i = 0; i < 4; i++)
    #pragma unroll
    for (int jj = 0; jj < 4; jj++) acc[i][jj] = (f32x4){0.f, 0.f, 0.f, 0.f};

  auto stage = [&](int bsel, int kt) {
    short* Ab = As + bsel * 8192 + wave * 512;
    short* Bb = Bs + bsel * 8192 + wave * 512;
    #pragma unroll
    for (int q = 0; q < 4; q++) {
      GLD_LDS16(agp[q] + kt, Ab + q * 2048);
      GLD_LDS16(bgp[q] + kt, Bb + q * 2048);
    }
  };

  stage(0, 0);
  stage(1, 64);

  // per-thread read bases (row stride 128 B); fragment rows differ by literal 2048 B
  unsigned aAddr0 = LDS_OFF(As) + (wm * 64 + l16) * 128;
  unsigned bAddr0 = LDS_OFF(Bs) + (wn * 64 + l16) * 128;
  unsigned soB[2];
  #pragma unroll
  for (int ks = 0; ks < 2; ks++) soB[ks] = (unsigned)((((ks << 2) | quad) ^ (l16 & 7)) << 4);

  const int NT = DM / 64;   // 8
  for (int t = 0; t < NT; t++) {
    if (t + 1 < NT) asm volatile("s_waitcnt vmcnt(8)" ::: "memory");
    else            asm volatile("s_waitcnt vmcnt(0)" ::: "memory");
    wg_barrier();              // tile t visible to all waves
    unsigned bo = (unsigned)((t & 1) * 16384);
    #pragma unroll
    for (int ks = 0; ks < 2; ks++) {
      unsigned aB = aAddr0 + bo + soB[ks];
      unsigned bB = bAddr0 + bo + soB[ks];
      bfrag afr[4], bfr[4];
      LDS_READ_OFF(afr[0], aB, "0");    LDS_READ_OFF(afr[1], aB, "2048");
      LDS_READ_OFF(afr[2], aB, "4096"); LDS_READ_OFF(afr[3], aB, "6144");
      LDS_READ_OFF(bfr[0], bB, "0");    LDS_READ_OFF(bfr[1], bB, "2048");
      LDS_READ_OFF(bfr[2], bB, "4096"); LDS_READ_OFF(bfr[3], bB, "6144");
      asm volatile("s_waitcnt lgkmcnt(0)" ::: "memory");
      __builtin_amdgcn_sched_barrier(0);
      __builtin_amdgcn_s_setprio(1);
      #pragma unroll
      for (int mi = 0; mi < 4; mi++)
        #pragma unroll
        for (int ni = 0; ni < 4; ni++)
          acc[mi][ni] = __builtin_amdgcn_mfma_f32_16x16x32_bf16(afr[mi], bfr[ni], acc[mi][ni], 0, 0, 0);
      __builtin_amdgcn_s_setprio(0);
    }
    wg_barrier();              // all waves done reading buf[t&1]
    if (t + 2 < NT) stage(t & 1, (t + 2) * 64);   // overwrite just-vacated buffer
  }

  // epilogue: gelu+bias -> LDS tile -> coalesced 16B stores
  short (*Hs)[136] = (short(*)[136])smem;   // 128*136*2 = 34816 B, LDS idle after loop
  const float* bb = b1 + (size_t)e * DFF;
  #pragma unroll
  for (int mi = 0; mi < 4; mi++) {
    int rl = wm * 64 + mi * 16 + quad * 4;
    #pragma unroll
    for (int ni = 0; ni < 4; ni++) {
      int cl = wn * 64 + ni * 16 + l16;
      float bv = bb[n0 + cl];
      #pragma unroll
      for (int r = 0; r < 4; r++)
        Hs[rl + r][cl] = f2bf(fast_gelu(acc[mi][ni][r] + bv));
    }
  }
  wg_barrier();
  int rbase0 = base + j * 128;
  int row16 = tid >> 4, colg = (tid & 15) * 8;
  #pragma unroll
  for (int ps = 0; ps < 8; ps++) {
    int row = ps * 16 + row16;
    u32x4 v = *(const u32x4*)&Hs[row][colg];
    *(u32x4*)(H + (size_t)(rbase0 + row) * DFF + n0 + colg) = v;
  }
}

// ---------------- sparse GEMM2, same structure, K=DFF ----------------
__global__ __launch_bounds__(256, 2) void gemm2_sp(const short* __restrict__ H,
                                                   const short* __restrict__ W2t,
                                                   const float* __restrict__ b2,
                                                   short* __restrict__ partial,
                                                   const float* __restrict__ wrow,
                                                   const int* __restrict__ meta) {
  __shared__ __align__(16) short smem[32768];
  short* As = smem;
  short* Bs = smem + 16384;
  int e = blockIdx.y >> 6, j = blockIdx.y & 63;
  int cnt = meta[e];
  if (j * 128 >= cnt) return;
  int base = meta[8 + e];
  int tid = threadIdx.x, wave = tid >> 6, lane = tid & 63;
  int wm = wave >> 1, wn = wave & 1, quad = lane >> 4, l16 = lane & 15;
  int n0 = blockIdx.x * 128;
  const short* Bt = W2t + (size_t)e * DM * DFF;

  const short* agp[4]; const short* bgp[4];
  #pragma unroll
  for (int q = 0; q < 4; q++) {
    int c = q * 256 + tid;
    int r = c >> 3, s = (c & 7) ^ (r & 7);
    agp[q] = H + (size_t)(base + j * 128 + r) * DFF + s * 8;
    bgp[q] = Bt + (size_t)(n0 + r) * DFF + s * 8;
  }

  f32x4 acc[4][4];
  #pragma unroll
  for (int i = 0; i < 4; i++)
    #pragma unroll
    for (int jj = 0; jj < 4; jj++) acc[i][jj] = (f32x4){0.f, 0.f, 0.f, 0.f};

  auto stage = [&](int bsel, int kt) {
    short* Ab = As + bsel * 8192 + wave * 512;
    short* Bb = Bs + bsel * 8192 + wave * 512;
    #pragma unroll
    for (int q = 0; q < 4; q++) {
      GLD_LDS16(agp[q] + kt, Ab + q * 2048);
      GLD_LDS16(bgp[q] + kt, Bb + q * 2048);
    }
  };

  stage(0, 0);
  stage(1, 64);

  unsigned aAddr0 = LDS_OFF(As) + (wm * 64 + l16) * 128;
  unsigned bAddr0 = LDS_OFF(Bs) + (wn * 64 + l16) * 128;
  unsigned soB[2];
  #pragma unroll
  for (int ks = 0; ks < 2; ks++) soB[ks] = (unsigned)((((ks << 2) | quad) ^ (l16 & 7)) << 4);

  const int NT = DFF / 64;  // 32
  for (int t = 0; t < NT; t++) {
    if (t + 1 < NT) asm volatile("s_waitcnt vmcnt(8)" ::: "memory");
    else            asm volatile("s_waitcnt vmcnt(0)" ::: "memory");
    wg_barrier();
    unsigned bo = (unsigned)((t & 1) * 16384);
    #pragma unroll
    for (int ks = 0; ks < 2; ks++) {
      unsigned aB = aAddr0 + bo + soB[ks];
      unsigned bB = bAddr0 + bo + soB[ks];
      bfrag afr[4], bfr[4];
      LDS_READ_OFF(afr[0], aB, "0");    LDS_READ_OFF(afr[1], aB, "2048");
      LDS_READ_OFF(afr[2], aB, "4096"); LDS_READ_OFF(afr[3], aB, "6144");
      LDS_READ_OFF(bfr[0], bB, "0");    LDS_READ_OFF(bfr[1], bB, "2048");
      LDS_READ_OFF(bfr[2], bB, "4096"); LDS_READ_OFF(bfr[3], bB, "6144");
      asm volatile("s_waitcnt lgkmcnt(0)" ::: "memory");
      __builtin_amdgcn_sched_barrier(0);
      __builtin_amdgcn_s_setprio(1);
      #pragma unroll
      for (int mi = 0; mi < 4; mi++)
        #pragma unroll
        for (int ni = 0; ni < 4; ni++)
          acc[mi][ni] = __builtin_amdgcn_mfma_f32_16x16x32_bf16(afr[mi], bfr[ni], acc[mi][ni], 0, 0, 0);
      __builtin_amdgcn_s_setprio(0);
    }
    wg_barrier();
    if (t + 2 < NT) stage(t & 1, (t + 2) * 64);
  }

  // epilogue: w*(acc+bias) -> LDS tile -> coalesced 16B stores
  short (*Hs)[136] = (short(*)[136])smem;
  const float* bb = b2 + (size_t)e * DM;
  int rbase0 = base + j * 128;
  #pragma unroll
  for (int mi = 0; mi < 4; mi++) {
    int rl = wm * 64 + mi * 16 + quad * 4;
    #pragma unroll
    for (int ni = 0; ni < 4; ni++) {
      int cl = wn * 64 + ni * 16 + l16;
      float bv = bb[n0 + cl];
      #pragma unroll
      for (int r = 0; r < 4; r++) {
        float w = wrow[rbase0 + rl + r];
        Hs[rl + r][cl] = f2bf(w * (acc[mi][ni][r] + bv));
      }
    }
  }
  wg_barrier();
  int row16 = tid >> 4, colg = (tid & 15) * 8;
  #pragma unroll
  for (int ps = 0; ps < 8; ps++) {
    int row = ps * 16 + row16;
    u32x4 v = *(const u32x4*)&Hs[row][colg];
    *(u32x4*)(partial + (size_t)(rbase0 + row) * DM + n0 + colg) = v;
  }
}

// ---------------- combine ----------------
__global__ __launch_bounds__(256) void combine_kernel(const short* __restrict__ partial,
                                                      const int* __restrict__ arow,
                                                      float* __restrict__ out) {
  int gid = blockIdx.x * 256 + threadIdx.x;
  int t = gid >> 6, c0 = (gid & 63) << 3;
  const int* ar = arow + t * 4;
  float o[8];
  #pragma unroll
  for (int k = 0; k < 8; k++) o[k] = 0.f;
  #pragma unroll
  for (int s = 0; s < 4; s++) {
    int a = ar[s];
    if (a >= 0) {
      union { u32x4 v; short s16[8]; } buf;
      buf.v = *(const u32x4*)(partial + (size_t)a * DM + c0);
      #pragma unroll
      for (int k = 0; k < 8; k++) o[k] += bf2f(buf.s16[k]);
    }
  }
  float* op = out + (size_t)t * DM + c0;
  *(f32x4*)op = (f32x4){o[0], o[1], o[2], o[3]};
  *(f32x4*)(op + 4) = (f32x4){o[4], o[5], o[6], o[7]};
}

extern "C" void kernel_launch(void* const* d_in, const int* in_sizes, int n_in,
                              void* d_out, int out_size, void* d_ws, size_t ws_size,
                              hipStream_t stream) {
  const float* x  = (const float*)d_in[0];
  const float* rw = (const float*)d_in[1];
  const float* W1 = (const float*)d_in[2];
  const float* b1 = (const float*)d_in[3];
  const float* W2 = (const float*)d_in[4];
  const float* b2 = (const float*)d_in[5];
  float* out = (float*)d_out;

  char* base_p = (char*)d_ws; char* p = base_p;
  auto carve = [&](size_t bytes) { char* r = p; p += (bytes + 255) & ~(size_t)255; return r; };
  short* xb    = (short*)carve((size_t)NTOK * DM * 2);
  short* w1b   = (short*)carve((size_t)NE * DM * DFF * 2);  // [e][DFF][DM]
  short* w2b   = (short*)carve((size_t)NE * DFF * DM * 2);  // [e][DM][DFF]
  int*   sel_e = (int*)carve((size_t)NTOK * 4 * 4);
  float* sel_w = (float*)carve((size_t)NTOK * 4 * 4);
  float* part  = (float*)carve(256 * 16 * 4);
  int*   meta  = (int*)carve(64 * 4);
  int*   arow  = (int*)carve((size_t)NTOK * 4 * 4);
  int*   mlist = (int*)carve((size_t)ROWCAP * 4);
  float* wrow  = (float*)carve((size_t)ROWCAP * 4);
  short* Hbig  = (short*)carve((size_t)ROWCAP * DFF * 2);
  short* partial = (short*)carve((size_t)ROWCAP * DM * 2);

  cvtT_kernel<<<dim3(DM / 32, DFF / 32, NE), 256, 0, stream>>>(W1, w1b, DM, DFF);
  cvtT_kernel<<<dim3(DFF / 32, DM / 32, NE), 256, 0, stream>>>(W2, w2b, DFF, DM);
  router_kernel<<<256, 256, 0, stream>>>(x, rw, xb, sel_e, sel_w, part);
  prep_kernel<<<1, 256, 0, stream>>>(part, out + (size_t)NTOK * DM, meta);
  build_kernel<<<256, 256, 0, stream>>>(sel_e, sel_w, meta, mlist, wrow, arow);
  gemm1_sp<<<dim3(DFF / 128, NE * 64), 256, 0, stream>>>(xb, w1b, b1, Hbig, mlist, meta);
  gemm2_sp<<<dim3(DM / 128, NE * 64), 256, 0, stream>>>(Hbig, w2b, b2, partial, wrow, meta);
  combine_kernel<<<NTOK * DM / 8 / 256, 256, 0, stream>>>(partial, arow, out);
}

// Round 9
// 368.639 us; speedup vs baseline: 1.2797x; 1.0386x over previous
//
#include <hip/hip_runtime.h>
#include <hip/hip_bf16.h>
#include <math.h>

#define NTOK 8192
#define DM 512
#define DFF 2048
#define NE 8
#define ROWCAP 33792   // 32768 assignments max + 8*128 granule padding

typedef __attribute__((ext_vector_type(8))) short bfrag;
typedef __attribute__((ext_vector_type(4))) float f32x4;
typedef __attribute__((ext_vector_type(4))) unsigned int u32x4;
typedef __attribute__((ext_vector_type(4))) short s16x4;

// async global->LDS, 16B/lane; LDS dest = wave-uniform base + lane*16 (global addr may be per-lane)
#define GLD_LDS16(gp, lp) __builtin_amdgcn_global_load_lds( \
    (const __attribute__((address_space(1))) void*)(gp),    \
    (__attribute__((address_space(3))) void*)(lp), 16, 0, 0)

// LDS byte offset of a generic pointer known to point into LDS
#define LDS_OFF(p) ((unsigned)(size_t)(__attribute__((address_space(3))) void*)(p))

// raw workgroup barrier WITHOUT the implicit s_waitcnt vmcnt(0) that __syncthreads carries.
__device__ __forceinline__ void wg_barrier() {
  asm volatile("" ::: "memory");
  __builtin_amdgcn_sched_barrier(0);
  __builtin_amdgcn_s_barrier();
  __builtin_amdgcn_sched_barrier(0);
  asm volatile("" ::: "memory");
}

// inline-asm ds_read_b128 with compile-time literal offset: invisible to the compiler's
// waitcnt pass (no implicit vmcnt(0) drain vs pending global_load_lds DMA), and the
// literal offset removes per-read VALU address adds.
// Caller MUST fence with s_waitcnt lgkmcnt(0) + sched_barrier(0) before consuming.
#define LDS_READ_OFF(dst, base, LIT) \
  asm volatile("ds_read_b128 %0, %1 offset:" LIT : "=v"(dst) : "v"(base))

__device__ __forceinline__ short f2bf(float f) {
  unsigned u = __builtin_bit_cast(unsigned, f);
  u += 0x7fffu + ((u >> 16) & 1u);
  return (short)(u >> 16);
}
__device__ __forceinline__ float bf2f(short s) {
  unsigned u = ((unsigned)(unsigned short)s) << 16;
  return __builtin_bit_cast(float, u);
}
// tanh-form GELU via hw exp2+rcp (~7 ops). max |diff vs erf-gelu| ~5e-4.
__device__ __forceinline__ float fast_gelu(float v) {
  float u = fmaf(v * v * v, 0.044715f, v) * 0.7978845608f;
  float ex = __builtin_amdgcn_exp2f(u * -2.8853900818f);
  return v * __builtin_amdgcn_rcpf(1.f + ex);
}

// ---------------- fp32 -> bf16 transpose-convert, W1 & W2 in ONE launch ----------------
__global__ __launch_bounds__(256) void cvtT2_kernel(const float* __restrict__ W1,
                                                    short* __restrict__ o1,
                                                    const float* __restrict__ W2,
                                                    short* __restrict__ o2) {
  __shared__ float t[32][33];
  int z = blockIdx.y;
  const float* in; short* o; int R, C, r0, c0;
  if (z < NE) {
    in = W1 + (size_t)z * DM * DFF; o = o1 + (size_t)z * DM * DFF; R = DM; C = DFF;
    r0 = (blockIdx.x & 15) * 32; c0 = (blockIdx.x >> 4) * 32;       // 16 x 64 tiles
  } else {
    z -= NE;
    in = W2 + (size_t)z * DFF * DM; o = o2 + (size_t)z * DFF * DM; R = DFF; C = DM;
    r0 = (blockIdx.x & 63) * 32; c0 = (blockIdx.x >> 6) * 32;       // 64 x 16 tiles
  }
  int tx = threadIdx.x & 31, ty = threadIdx.x >> 5;
  #pragma unroll
  for (int i = 0; i < 32; i += 8)
    t[ty + i][tx] = in[(size_t)(r0 + ty + i) * C + c0 + tx];
  __syncthreads();
  int tx4 = threadIdx.x & 7, oc = threadIdx.x >> 3;
  s16x4 v;
  #pragma unroll
  for (int jj = 0; jj < 4; jj++) v[jj] = f2bf(t[tx4 * 4 + jj][oc]);
  *(s16x4*)(o + (size_t)(c0 + oc) * R + r0 + tx4 * 4) = v;
}

// ---------------- router (fused: also emits xb = bf16(x)) ----------------
__global__ __launch_bounds__(256) void router_kernel(const float* __restrict__ x,
                                                     const float* __restrict__ rw,
                                                     short* __restrict__ xb,
                                                     int* __restrict__ sel_e,
                                                     float* __restrict__ sel_w,
                                                     float* __restrict__ part) {
  __shared__ float s_cnt[NE], s_ps[NE];
  int tid = threadIdx.x;
  if (tid < NE) { s_cnt[tid] = 0.f; s_ps[tid] = 0.f; }
  __syncthreads();
  int wave = tid >> 6, lane = tid & 63;
  float myc[NE], myp[NE];
  #pragma unroll
  for (int e = 0; e < NE; e++) { myc[e] = 0.f; myp[e] = 0.f; }

  for (int i = 0; i < 8; i++) {
    int token = blockIdx.x * 32 + wave * 8 + i;
    const float* xt = x + (size_t)token * DM;
    float acc[NE];
    #pragma unroll
    for (int e = 0; e < NE; e++) acc[e] = 0.f;
    #pragma unroll
    for (int kk = 0; kk < DM / 64; kk++) {
      int k = kk * 64 + lane;
      float xv = xt[k];
      xb[(size_t)token * DM + k] = f2bf(xv);   // fused fp32->bf16 emit
      f32x4 r0 = *(const f32x4*)(rw + k * NE);
      f32x4 r1 = *(const f32x4*)(rw + k * NE + 4);
      acc[0] += xv * r0[0]; acc[1] += xv * r0[1]; acc[2] += xv * r0[2]; acc[3] += xv * r0[3];
      acc[4] += xv * r1[0]; acc[5] += xv * r1[1]; acc[6] += xv * r1[2]; acc[7] += xv * r1[3];
    }
    #pragma unroll
    for (int off = 32; off >= 1; off >>= 1) {
      #pragma unroll
      for (int e = 0; e < NE; e++) acc[e] += __shfl_xor(acc[e], off, 64);
    }
    float mx = acc[0];
    #pragma unroll
    for (int e = 1; e < NE; e++) mx = fmaxf(mx, acc[e]);
    float p[NE]; float sum = 0.f;
    #pragma unroll
    for (int e = 0; e < NE; e++) { p[e] = expf(acc[e] - mx); sum += p[e]; }
    float inv = 1.f / sum;
    #pragma unroll
    for (int e = 0; e < NE; e++) p[e] *= inv;
    float sp[4]; int si[4]; unsigned used = 0;
    #pragma unroll
    for (int s = 0; s < 4; s++) {
      float bp = -1.f; int bi = 0;
      #pragma unroll
      for (int e = 0; e < NE; e++)
        if (!((used >> e) & 1u) && p[e] > bp) { bp = p[e]; bi = e; }
      used |= 1u << bi; sp[s] = bp; si[s] = bi;
    }
    float csum = 0.f, wsum = 0.f; bool keep[4];
    #pragma unroll
    for (int s = 0; s < 4; s++) {
      keep[s] = (s < 1) || (csum < 0.9f);
      csum += sp[s];
      if (keep[s]) wsum += sp[s];
    }
    wsum = fmaxf(wsum, 1e-9f);
    if (lane == 0) {
      #pragma unroll
      for (int s = 0; s < 4; s++) {
        sel_e[token * 4 + s] = keep[s] ? si[s] : -1;
        sel_w[token * 4 + s] = keep[s] ? sp[s] / wsum : 0.f;
      }
      #pragma unroll
      for (int e = 0; e < NE; e++) myp[e] += p[e];
      #pragma unroll
      for (int s = 0; s < 4; s++) if (keep[s]) myc[si[s]] += 1.f;
    }
  }
  if (lane == 0) {
    #pragma unroll
    for (int e = 0; e < NE; e++) { atomicAdd(&s_cnt[e], myc[e]); atomicAdd(&s_ps[e], myp[e]); }
  }
  __syncthreads();
  if (tid < NE) {
    part[blockIdx.x * 16 + tid] = s_cnt[tid];
    part[blockIdx.x * 16 + 8 + tid] = s_ps[tid];
  }
}

// ---------------- prep: aux scalar + expert bases (128-aligned), parallel reduce ----------------
__global__ __launch_bounds__(256) void prep_kernel(const float* __restrict__ part,
                                                   float* __restrict__ auxp,
                                                   int* __restrict__ meta) {
  __shared__ float red2[16][16];   // [group][idx]
  __shared__ float red[16];
  int tid = threadIdx.x;
  int idx = tid & 15, g = tid >> 4;      // 16 groups, each sums 16 router blocks
  float s = 0.f;
  #pragma unroll
  for (int b = 0; b < 16; b++) s += part[(g * 16 + b) * 16 + idx];
  red2[g][idx] = s;
  __syncthreads();
  if (tid < 16) {
    float t = 0.f;
    #pragma unroll
    for (int g2 = 0; g2 < 16; g2++) t += red2[g2][tid];
    red[tid] = t;
  }
  __syncthreads();
  if (tid == 0) {
    float tot = 0.f;
    for (int e = 0; e < NE; e++) tot += red[e];
    float t = fmaxf(tot, 1.f), s2 = 0.f;
    for (int e = 0; e < NE; e++) s2 += (red[e] / t) * (red[NE + e] / (float)NTOK);
    auxp[0] = 0.01f * (float)NE * s2;
    int off = 0;
    for (int e = 0; e < NE; e++) {
      int c = (int)(red[e] + 0.5f);
      meta[e] = c; meta[8 + e] = off;
      off += (c + 127) & ~127;   // 128-granule padding (M-tile = 128)
    }
  }
  if (tid < NE) meta[16 + tid] = 0;
}

// ---------------- build compact assignment lists ----------------
__global__ __launch_bounds__(256) void build_kernel(const int* __restrict__ sel_e,
                                                    const float* __restrict__ sel_w,
                                                    int* __restrict__ meta,
                                                    int* __restrict__ mlist,
                                                    float* __restrict__ wrow,
                                                    int* __restrict__ arow) {
  __shared__ int lcnt[NE], roff[NE];
  int tid = threadIdx.x;
  if (tid < NE) lcnt[tid] = 0;
  __syncthreads();
  int t = blockIdx.x * 32 + tid;
  int slots[4], es[4];
  bool active = tid < 32;
  if (active) {
    #pragma unroll
    for (int s = 0; s < 4; s++) {
      es[s] = sel_e[t * 4 + s];
      slots[s] = (es[s] >= 0) ? atomicAdd(&lcnt[es[s]], 1) : -1;
    }
  }
  __syncthreads();
  if (tid < NE) roff[tid] = atomicAdd(&meta[16 + tid], lcnt[tid]);
  __syncthreads();
  if (active) {
    #pragma unroll
    for (int s = 0; s < 4; s++) {
      int e = es[s];
      if (e >= 0) {
        int hrow = meta[8 + e] + roff[e] + slots[s];
        mlist[hrow] = t;
        wrow[hrow] = sel_w[t * 4 + s];
        arow[t * 4 + s] = hrow;
      } else {
        arow[t * 4 + s] = -1;
      }
    }
  }
}

// ---------------- sparse GEMM1, 128x128 tile, BK=64, counted-vmcnt + asm ds_read ----------------
// R8-verified K-loop + LDS epilogue. NEW: chunked XCD swizzle (T1) — hardware round-robins
// linear workgroup id across the 8 XCDs, so lid = (hid&7)*(nwg/8) + hid>>3 gives each XCD a
// CONTIGUOUS logical range. The 16 logical-consecutive blocks sharing an A-tile then run on
// ONE XCD -> A-tile gathered into that L2 once (was: 8 XCD copies, 90 MB over-fetch), and
// the expert's 2 MB W1 slice stays L2-resident across its j-tiles. nwg = 8192 (div by 8).
__global__ __launch_bounds__(256, 2) void gemm1_sp(const short* __restrict__ A,
                                                   const short* __restrict__ W1t,
                                                   const float* __restrict__ b1,
                                                   short* __restrict__ H,
                                                   const int* __restrict__ mlist,
                                                   const int* __restrict__ meta) {
  __shared__ __align__(16) short smem[32768];   // 64 KB: As | Bs, reused as Hs in epilogue
  short* As = smem;
  short* Bs = smem + 16384;
  unsigned nwg = gridDim.x * gridDim.y;                        // 8192
  unsigned hid = blockIdx.y * gridDim.x + blockIdx.x;
  unsigned lid = (hid & 7) * (nwg >> 3) + (hid >> 3);          // chunked XCD swizzle
  int xblk = lid & 15, yblk = lid >> 4;                        // gridDim.x == 16
  int e = yblk >> 6, j = yblk & 63;
  int cnt = meta[e];
  if (j * 128 >= cnt) return;
  int base = meta[8 + e];
  int tid = threadIdx.x, wave = tid >> 6, lane = tid & 63;
  int wm = wave >> 1, wn = wave & 1, quad = lane >> 4, l16 = lane & 15;
  int n0 = xblk * 128;
  const short* Bt = W1t + (size_t)e * DFF * DM;

  // staging: chunk c = q*256 + tid; row r = c>>3; logical slot s = (c&7)^(r&7) at source
  const short* agp[4]; const short* bgp[4];
  #pragma unroll
  for (int q = 0; q < 4; q++) {
    int c = q * 256 + tid;
    int r = c >> 3, s = (c & 7) ^ (r & 7);
    int rl = j * 128 + r;
    int tok = mlist[base + (rl < cnt ? rl : cnt - 1)];
    agp[q] = A + (size_t)tok * DM + s * 8;
    bgp[q] = Bt + (size_t)(n0 + r) * DM + s * 8;
  }

  f32x4 acc[4][4];
  #pragma unroll
  for (int i = 0; i < 4; i++)
    #pragma unroll
    for (int jj = 0; jj < 4; jj++) acc[i][jj] = (f32x4){0.f, 0.f, 0.f, 0.f};

  auto stage = [&](int bsel, int kt) {
    short* Ab = As + bsel * 8192 + wave * 512;
    short* Bb = Bs + bsel * 8192 + wave * 512;
    #pragma unroll
    for (int q = 0; q < 4; q++) {
      GLD_LDS16(agp[q] + kt, Ab + q * 2048);
      GLD_LDS16(bgp[q] + kt, Bb + q * 2048);
    }
  };

  stage(0, 0);
  stage(1, 64);

  // per-thread read bases (row stride 128 B); fragment rows differ by literal 2048 B
  unsigned aAddr0 = LDS_OFF(As) + (wm * 64 + l16) * 128;
  unsigned bAddr0 = LDS_OFF(Bs) + (wn * 64 + l16) * 128;
  unsigned soB[2];
  #pragma unroll
  for (int ks = 0; ks < 2; ks++) soB[ks] = (unsigned)((((ks << 2) | quad) ^ (l16 & 7)) << 4);

  const int NT = DM / 64;   // 8
  for (int t = 0; t < NT; t++) {
    if (t + 1 < NT) asm volatile("s_waitcnt vmcnt(8)" ::: "memory");
    else            asm volatile("s_waitcnt vmcnt(0)" ::: "memory");
    wg_barrier();              // tile t visible to all waves
    unsigned bo = (unsigned)((t & 1) * 16384);
    #pragma unroll
    for (int ks = 0; ks < 2; ks++) {
      unsigned aB = aAddr0 + bo + soB[ks];
      unsigned bB = bAddr0 + bo + soB[ks];
      bfrag afr[4], bfr[4];
      LDS_READ_OFF(afr[0], aB, "0");    LDS_READ_OFF(afr[1], aB, "2048");
      LDS_READ_OFF(afr[2], aB, "4096"); LDS_READ_OFF(afr[3], aB, "6144");
      LDS_READ_OFF(bfr[0], bB, "0");    LDS_READ_OFF(bfr[1], bB, "2048");
      LDS_READ_OFF(bfr[2], bB, "4096"); LDS_READ_OFF(bfr[3], bB, "6144");
      asm volatile("s_waitcnt lgkmcnt(0)" ::: "memory");
      __builtin_amdgcn_sched_barrier(0);
      __builtin_amdgcn_s_setprio(1);
      #pragma unroll
      for (int mi = 0; mi < 4; mi++)
        #pragma unroll
        for (int ni = 0; ni < 4; ni++)
          acc[mi][ni] = __builtin_amdgcn_mfma_f32_16x16x32_bf16(afr[mi], bfr[ni], acc[mi][ni], 0, 0, 0);
      __builtin_amdgcn_s_setprio(0);
    }
    wg_barrier();              // all waves done reading buf[t&1]
    if (t + 2 < NT) stage(t & 1, (t + 2) * 64);   // overwrite just-vacated buffer
  }

  // epilogue: gelu+bias -> LDS tile -> coalesced 16B stores
  short (*Hs)[136] = (short(*)[136])smem;   // 128*136*2 = 34816 B, LDS idle after loop
  const float* bb = b1 + (size_t)e * DFF;
  #pragma unroll
  for (int mi = 0; mi < 4; mi++) {
    int rl = wm * 64 + mi * 16 + quad * 4;
    #pragma unroll
    for (int ni = 0; ni < 4; ni++) {
      int cl = wn * 64 + ni * 16 + l16;
      float bv = bb[n0 + cl];
      #pragma unroll
      for (int r = 0; r < 4; r++)
        Hs[rl + r][cl] = f2bf(fast_gelu(acc[mi][ni][r] + bv));
    }
  }
  wg_barrier();
  int rbase0 = base + j * 128;
  int row16 = tid >> 4, colg = (tid & 15) * 8;
  #pragma unroll
  for (int ps = 0; ps < 8; ps++) {
    int row = ps * 16 + row16;
    u32x4 v = *(const u32x4*)&Hs[row][colg];
    *(u32x4*)(H + (size_t)(rbase0 + row) * DFF + n0 + colg) = v;
  }
}

// ---------------- sparse GEMM2, same structure, K=DFF ----------------
__global__ __launch_bounds__(256, 2) void gemm2_sp(const short* __restrict__ H,
                                                   const short* __restrict__ W2t,
                                                   const float* __restrict__ b2,
                                                   short* __restrict__ partial,
                                                   const float* __restrict__ wrow,
                                                   const int* __restrict__ meta) {
  __shared__ __align__(16) short smem[32768];
  short* As = smem;
  short* Bs = smem + 16384;
  unsigned nwg = gridDim.x * gridDim.y;                        // 2048
  unsigned hid = blockIdx.y * gridDim.x + blockIdx.x;
  unsigned lid = (hid & 7) * (nwg >> 3) + (hid >> 3);          // chunked XCD swizzle
  int xblk = lid & 3, yblk = lid >> 2;                         // gridDim.x == 4
  int e = yblk >> 6, j = yblk & 63;
  int cnt = meta[e];
  if (j * 128 >= cnt) return;
  int base = meta[8 + e];
  int tid = threadIdx.x, wave = tid >> 6, lane = tid & 63;
  int wm = wave >> 1, wn = wave & 1, quad = lane >> 4, l16 = lane & 15;
  int n0 = xblk * 128;
  const short* Bt = W2t + (size_t)e * DM * DFF;

  const short* agp[4]; const short* bgp[4];
  #pragma unroll
  for (int q = 0; q < 4; q++) {
    int c = q * 256 + tid;
    int r = c >> 3, s = (c & 7) ^ (r & 7);
    agp[q] = H + (size_t)(base + j * 128 + r) * DFF + s * 8;
    bgp[q] = Bt + (size_t)(n0 + r) * DFF + s * 8;
  }

  f32x4 acc[4][4];
  #pragma unroll
  for (int i = 0; i < 4; i++)
    #pragma unroll
    for (int jj = 0; jj < 4; jj++) acc[i][jj] = (f32x4){0.f, 0.f, 0.f, 0.f};

  auto stage = [&](int bsel, int kt) {
    short* Ab = As + bsel * 8192 + wave * 512;
    short* Bb = Bs + bsel * 8192 + wave * 512;
    #pragma unroll
    for (int q = 0; q < 4; q++) {
      GLD_LDS16(agp[q] + kt, Ab + q * 2048);
      GLD_LDS16(bgp[q] + kt, Bb + q * 2048);
    }
  };

  stage(0, 0);
  stage(1, 64);

  unsigned aAddr0 = LDS_OFF(As) + (wm * 64 + l16) * 128;
  unsigned bAddr0 = LDS_OFF(Bs) + (wn * 64 + l16) * 128;
  unsigned soB[2];
  #pragma unroll
  for (int ks = 0; ks < 2; ks++) soB[ks] = (unsigned)((((ks << 2) | quad) ^ (l16 & 7)) << 4);

  const int NT = DFF / 64;  // 32
  for (int t = 0; t < NT; t++) {
    if (t + 1 < NT) asm volatile("s_waitcnt vmcnt(8)" ::: "memory");
    else            asm volatile("s_waitcnt vmcnt(0)" ::: "memory");
    wg_barrier();
    unsigned bo = (unsigned)((t & 1) * 16384);
    #pragma unroll
    for (int ks = 0; ks < 2; ks++) {
      unsigned aB = aAddr0 + bo + soB[ks];
      unsigned bB = bAddr0 + bo + soB[ks];
      bfrag afr[4], bfr[4];
      LDS_READ_OFF(afr[0], aB, "0");    LDS_READ_OFF(afr[1], aB, "2048");
      LDS_READ_OFF(afr[2], aB, "4096"); LDS_READ_OFF(afr[3], aB, "6144");
      LDS_READ_OFF(bfr[0], bB, "0");    LDS_READ_OFF(bfr[1], bB, "2048");
      LDS_READ_OFF(bfr[2], bB, "4096"); LDS_READ_OFF(bfr[3], bB, "6144");
      asm volatile("s_waitcnt lgkmcnt(0)" ::: "memory");
      __builtin_amdgcn_sched_barrier(0);
      __builtin_amdgcn_s_setprio(1);
      #pragma unroll
      for (int mi = 0; mi < 4; mi++)
        #pragma unroll
        for (int ni = 0; ni < 4; ni++)
          acc[mi][ni] = __builtin_amdgcn_mfma_f32_16x16x32_bf16(afr[mi], bfr[ni], acc[mi][ni], 0, 0, 0);
      __builtin_amdgcn_s_setprio(0);
    }
    wg_barrier();
    if (t + 2 < NT) stage(t & 1, (t + 2) * 64);
  }

  // epilogue: w*(acc+bias) -> LDS tile -> coalesced 16B stores
  short (*Hs)[136] = (short(*)[136])smem;
  const float* bb = b2 + (size_t)e * DM;
  int rbase0 = base + j * 128;
  #pragma unroll
  for (int mi = 0; mi < 4; mi++) {
    int rl = wm * 64 + mi * 16 + quad * 4;
    #pragma unroll
    for (int ni = 0; ni < 4; ni++) {
      int cl = wn * 64 + ni * 16 + l16;
      float bv = bb[n0 + cl];
      #pragma unroll
      for (int r = 0; r < 4; r++) {
        float w = wrow[rbase0 + rl + r];
        Hs[rl + r][cl] = f2bf(w * (acc[mi][ni][r] + bv));
      }
    }
  }
  wg_barrier();
  int row16 = tid >> 4, colg = (tid & 15) * 8;
  #pragma unroll
  for (int ps = 0; ps < 8; ps++) {
    int row = ps * 16 + row16;
    u32x4 v = *(const u32x4*)&Hs[row][colg];
    *(u32x4*)(partial + (size_t)(rbase0 + row) * DM + n0 + colg) = v;
  }
}

// ---------------- combine ----------------
__global__ __launch_bounds__(256) void combine_kernel(const short* __restrict__ partial,
                                                      const int* __restrict__ arow,
                                                      float* __restrict__ out) {
  int gid = blockIdx.x * 256 + threadIdx.x;
  int t = gid >> 6, c0 = (gid & 63) << 3;
  const int* ar = arow + t * 4;
  float o[8];
  #pragma unroll
  for (int k = 0; k < 8; k++) o[k] = 0.f;
  #pragma unroll
  for (int s = 0; s < 4; s++) {
    int a = ar[s];
    if (a >= 0) {
      union { u32x4 v; short s16[8]; } buf;
      buf.v = *(const u32x4*)(partial + (size_t)a * DM + c0);
      #pragma unroll
      for (int k = 0; k < 8; k++) o[k] += bf2f(buf.s16[k]);
    }
  }
  float* op = out + (size_t)t * DM + c0;
  *(f32x4*)op = (f32x4){o[0], o[1], o[2], o[3]};
  *(f32x4*)(op + 4) = (f32x4){o[4], o[5], o[6], o[7]};
}

extern "C" void kernel_launch(void* const* d_in, const int* in_sizes, int n_in,
                              void* d_out, int out_size, void* d_ws, size_t ws_size,
                              hipStream_t stream) {
  const float* x  = (const float*)d_in[0];
  const float* rw = (const float*)d_in[1];
  const float* W1 = (const float*)d_in[2];
  const float* b1 = (const float*)d_in[3];
  const float* W2 = (const float*)d_in[4];
  const float* b2 = (const float*)d_in[5];
  float* out = (float*)d_out;

  char* base_p = (char*)d_ws; char* p = base_p;
  auto carve = [&](size_t bytes) { char* r = p; p += (bytes + 255) & ~(size_t)255; return r; };
  short* xb    = (short*)carve((size_t)NTOK * DM * 2);
  short* w1b   = (short*)carve((size_t)NE * DM * DFF * 2);  // [e][DFF][DM]
  short* w2b   = (short*)carve((size_t)NE * DFF * DM * 2);  // [e][DM][DFF]
  int*   sel_e = (int*)carve((size_t)NTOK * 4 * 4);
  float* sel_w = (float*)carve((size_t)NTOK * 4 * 4);
  float* part  = (float*)carve(256 * 16 * 4);
  int*   meta  = (int*)carve(64 * 4);
  int*   arow  = (int*)carve((size_t)NTOK * 4 * 4);
  int*   mlist = (int*)carve((size_t)ROWCAP * 4);
  float* wrow  = (float*)carve((size_t)ROWCAP * 4);
  short* Hbig  = (short*)carve((size_t)ROWCAP * DFF * 2);
  short* partial = (short*)carve((size_t)ROWCAP * DM * 2);

  cvtT2_kernel<<<dim3(1024, NE * 2), 256, 0, stream>>>(W1, w1b, W2, w2b);
  router_kernel<<<256, 256, 0, stream>>>(x, rw, xb, sel_e, sel_w, part);
  prep_kernel<<<1, 256, 0, stream>>>(part, out + (size_t)NTOK * DM, meta);
  build_kernel<<<256, 256, 0, stream>>>(sel_e, sel_w, meta, mlist, wrow, arow);
  gemm1_sp<<<dim3(DFF / 128, NE * 64), 256, 0, stream>>>(xb, w1b, b1, Hbig, mlist, meta);
  gemm2_sp<<<dim3(DM / 128, NE * 64), 256, 0, stream>>>(Hbig, w2b, b2, partial, wrow, meta);
  combine_kernel<<<NTOK * DM / 8 / 256, 256, 0, stream>>>(partial, arow, out);
}

// Round 11
// 365.586 us; speedup vs baseline: 1.2904x; 1.0084x over previous
//
#include <hip/hip_runtime.h>
#include <hip/hip_bf16.h>
#include <math.h>

#define NTOK 8192
#define DM 512
#define DFF 2048
#define NE 8
#define ROWCAP 33792   // 32768 assignments max + 8*128 granule padding

typedef __attribute__((ext_vector_type(8))) short bfrag;
typedef __attribute__((ext_vector_type(4))) float f32x4;
typedef __attribute__((ext_vector_type(4))) unsigned int u32x4;
typedef __attribute__((ext_vector_type(4))) short s16x4;

// async global->LDS, 16B/lane; LDS dest = wave-uniform base + lane*16 (global addr may be per-lane)
#define GLD_LDS16(gp, lp) __builtin_amdgcn_global_load_lds( \
    (const __attribute__((address_space(1))) void*)(gp),    \
    (__attribute__((address_space(3))) void*)(lp), 16, 0, 0)

// LDS byte offset of a generic pointer known to point into LDS
#define LDS_OFF(p) ((unsigned)(size_t)(__attribute__((address_space(3))) void*)(p))

// workgroup barrier WITHOUT an implicit vmcnt(0) drain (keeps global_load_lds prefetches
// in flight) but WITH lgkmcnt(0): ISA requires draining LDS ops before s_barrier when
// other waves will read the data (epilogue ds_write -> cross-wave read). In the K-loop
// this is a no-op (ds_reads are drained before MFMA; DMA counts in vmcnt only).
__device__ __forceinline__ void wg_barrier() {
  asm volatile("" ::: "memory");
  __builtin_amdgcn_sched_barrier(0);
  asm volatile("s_waitcnt lgkmcnt(0)" ::: "memory");
  __builtin_amdgcn_s_barrier();
  __builtin_amdgcn_sched_barrier(0);
  asm volatile("" ::: "memory");
}

// inline-asm ds_read_b128 with compile-time literal offset: invisible to the compiler's
// waitcnt pass (no implicit vmcnt(0) drain vs pending global_load_lds DMA), and the
// literal offset removes per-read VALU address adds.
// Caller MUST fence with s_waitcnt lgkmcnt(0) + sched_barrier(0) before consuming.
#define LDS_READ_OFF(dst, base, LIT) \
  asm volatile("ds_read_b128 %0, %1 offset:" LIT : "=v"(dst) : "v"(base))

__device__ __forceinline__ short f2bf(float f) {
  unsigned u = __builtin_bit_cast(unsigned, f);
  u += 0x7fffu + ((u >> 16) & 1u);
  return (short)(u >> 16);
}
__device__ __forceinline__ float bf2f(short s) {
  unsigned u = ((unsigned)(unsigned short)s) << 16;
  return __builtin_bit_cast(float, u);
}
// tanh-form GELU via hw exp2+rcp (~7 ops). max |diff vs erf-gelu| ~5e-4.
__device__ __forceinline__ float fast_gelu(float v) {
  float u = fmaf(v * v * v, 0.044715f, v) * 0.7978845608f;
  float ex = __builtin_amdgcn_exp2f(u * -2.8853900818f);
  return v * __builtin_amdgcn_rcpf(1.f + ex);
}

// ---------------- fp32 -> bf16 transpose-convert, W1 & W2 in ONE launch ----------------
// 64(rows) x 32(cols) input tiles: output rows are (c0+oc) with 64 shorts = 128 B = one
// full cache line per row (8 threads x 16B bfrag stores). Loads stay 128 B segments.
__global__ __launch_bounds__(256) void cvtT2_kernel(const float* __restrict__ W1,
                                                    short* __restrict__ o1,
                                                    const float* __restrict__ W2,
                                                    short* __restrict__ o2) {
  __shared__ float t[64][33];
  int z = blockIdx.y;
  const float* in; short* o; int R, C, r0, c0;
  if (z < NE) {
    in = W1 + (size_t)z * DM * DFF; o = o1 + (size_t)z * DM * DFF; R = DM; C = DFF;
    r0 = (blockIdx.x & 7) * 64; c0 = (blockIdx.x >> 3) * 32;        // 8 x 64 tiles
  } else {
    z -= NE;
    in = W2 + (size_t)z * DFF * DM; o = o2 + (size_t)z * DFF * DM; R = DFF; C = DM;
    r0 = (blockIdx.x & 31) * 64; c0 = (blockIdx.x >> 5) * 32;       // 32 x 16 tiles
  }
  int tx = threadIdx.x & 31, ty = threadIdx.x >> 5;   // ty 0..7
  #pragma unroll
  for (int i = 0; i < 64; i += 8)
    t[ty + i][tx] = in[(size_t)(r0 + ty + i) * C + c0 + tx];
  __syncthreads();
  int tseg = threadIdx.x & 7, oc = threadIdx.x >> 3;  // oc 0..31
  bfrag v;
  #pragma unroll
  for (int jj = 0; jj < 8; jj++) v[jj] = f2bf(t[tseg * 8 + jj][oc]);
  *(bfrag*)(o + (size_t)(c0 + oc) * R + r0 + tseg * 8) = v;
}

// ---------------- router (fused: also emits xb = bf16(x)) ----------------
__global__ __launch_bounds__(256) void router_kernel(const float* __restrict__ x,
                                                     const float* __restrict__ rw,
                                                     short* __restrict__ xb,
                                                     int* __restrict__ sel_e,
                                                     float* __restrict__ sel_w,
                                                     float* __restrict__ part) {
  __shared__ float s_cnt[NE], s_ps[NE];
  int tid = threadIdx.x;
  if (tid < NE) { s_cnt[tid] = 0.f; s_ps[tid] = 0.f; }
  __syncthreads();
  int wave = tid >> 6, lane = tid & 63;
  float myc[NE], myp[NE];
  #pragma unroll
  for (int e = 0; e < NE; e++) { myc[e] = 0.f; myp[e] = 0.f; }

  for (int i = 0; i < 8; i++) {
    int token = blockIdx.x * 32 + wave * 8 + i;
    const float* xt = x + (size_t)token * DM;
    float acc[NE];
    #pragma unroll
    for (int e = 0; e < NE; e++) acc[e] = 0.f;
    #pragma unroll
    for (int kk = 0; kk < DM / 64; kk++) {
      int k = kk * 64 + lane;
      float xv = xt[k];
      xb[(size_t)token * DM + k] = f2bf(xv);   // fused fp32->bf16 emit
      f32x4 r0 = *(const f32x4*)(rw + k * NE);
      f32x4 r1 = *(const f32x4*)(rw + k * NE + 4);
      acc[0] += xv * r0[0]; acc[1] += xv * r0[1]; acc[2] += xv * r0[2]; acc[3] += xv * r0[3];
      acc[4] += xv * r1[0]; acc[5] += xv * r1[1]; acc[6] += xv * r1[2]; acc[7] += xv * r1[3];
    }
    #pragma unroll
    for (int off = 32; off >= 1; off >>= 1) {
      #pragma unroll
      for (int e = 0; e < NE; e++) acc[e] += __shfl_xor(acc[e], off, 64);
    }
    float mx = acc[0];
    #pragma unroll
    for (int e = 1; e < NE; e++) mx = fmaxf(mx, acc[e]);
    float p[NE]; float sum = 0.f;
    #pragma unroll
    for (int e = 0; e < NE; e++) { p[e] = expf(acc[e] - mx); sum += p[e]; }
    float inv = 1.f / sum;
    #pragma unroll
    for (int e = 0; e < NE; e++) p[e] *= inv;
    float sp[4]; int si[4]; unsigned used = 0;
    #pragma unroll
    for (int s = 0; s < 4; s++) {
      float bp = -1.f; int bi = 0;
      #pragma unroll
      for (int e = 0; e < NE; e++)
        if (!((used >> e) & 1u) && p[e] > bp) { bp = p[e]; bi = e; }
      used |= 1u << bi; sp[s] = bp; si[s] = bi;
    }
    float csum = 0.f, wsum = 0.f; bool keep[4];
    #pragma unroll
    for (int s = 0; s < 4; s++) {
      keep[s] = (s < 1) || (csum < 0.9f);
      csum += sp[s];
      if (keep[s]) wsum += sp[s];
    }
    wsum = fmaxf(wsum, 1e-9f);
    if (lane == 0) {
      #pragma unroll
      for (int s = 0; s < 4; s++) {
        sel_e[token * 4 + s] = keep[s] ? si[s] : -1;
        sel_w[token * 4 + s] = keep[s] ? sp[s] / wsum : 0.f;
      }
      #pragma unroll
      for (int e = 0; e < NE; e++) myp[e] += p[e];
      #pragma unroll
      for (int s = 0; s < 4; s++) if (keep[s]) myc[si[s]] += 1.f;
    }
  }
  if (lane == 0) {
    #pragma unroll
    for (int e = 0; e < NE; e++) { atomicAdd(&s_cnt[e], myc[e]); atomicAdd(&s_ps[e], myp[e]); }
  }
  __syncthreads();
  if (tid < NE) {
    part[blockIdx.x * 16 + tid] = s_cnt[tid];
    part[blockIdx.x * 16 + 8 + tid] = s_ps[tid];
  }
}

// ---------------- prep: aux scalar + expert bases (128-aligned), parallel reduce ----------------
__global__ __launch_bounds__(256) void prep_kernel(const float* __restrict__ part,
                                                   float* __restrict__ auxp,
                                                   int* __restrict__ meta) {
  __shared__ float red2[16][16];   // [group][idx]
  __shared__ float red[16];
  int tid = threadIdx.x;
  int idx = tid & 15, g = tid >> 4;      // 16 groups, each sums 16 router blocks
  float s = 0.f;
  #pragma unroll
  for (int b = 0; b < 16; b++) s += part[(g * 16 + b) * 16 + idx];
  red2[g][idx] = s;
  __syncthreads();
  if (tid < 16) {
    float t = 0.f;
    #pragma unroll
    for (int g2 = 0; g2 < 16; g2++) t += red2[g2][tid];
    red[tid] = t;
  }
  __syncthreads();
  if (tid == 0) {
    float tot = 0.f;
    for (int e = 0; e < NE; e++) tot += red[e];
    float t = fmaxf(tot, 1.f), s2 = 0.f;
    for (int e = 0; e < NE; e++) s2 += (red[e] / t) * (red[NE + e] / (float)NTOK);
    auxp[0] = 0.01f * (float)NE * s2;
    int off = 0;
    for (int e = 0; e < NE; e++) {
      int c = (int)(red[e] + 0.5f);
      meta[e] = c; meta[8 + e] = off;
      off += (c + 127) & ~127;   // 128-granule padding (M-tile = 128)
    }
  }
  if (tid < NE) meta[16 + tid] = 0;
}

// ---------------- build compact assignment lists ----------------
__global__ __launch_bounds__(256) void build_kernel(const int* __restrict__ sel_e,
                                                    const float* __restrict__ sel_w,
                                                    int* __restrict__ meta,
                                                    int* __restrict__ mlist,
                                                    float* __restrict__ wrow,
                                                    int* __restrict__ arow) {
  __shared__ int lcnt[NE], roff[NE];
  int tid = threadIdx.x;
  if (tid < NE) lcnt[tid] = 0;
  __syncthreads();
  int t = blockIdx.x * 32 + tid;
  int slots[4], es[4];
  bool active = tid < 32;
  if (active) {
    #pragma unroll
    for (int s = 0; s < 4; s++) {
      es[s] = sel_e[t * 4 + s];
      slots[s] = (es[s] >= 0) ? atomicAdd(&lcnt[es[s]], 1) : -1;
    }
  }
  __syncthreads();
  if (tid < NE) roff[tid] = atomicAdd(&meta[16 + tid], lcnt[tid]);
  __syncthreads();
  if (active) {
    #pragma unroll
    for (int s = 0; s < 4; s++) {
      int e = es[s];
      if (e >= 0) {
        int hrow = meta[8 + e] + roff[e] + slots[s];
        mlist[hrow] = t;
        wrow[hrow] = sel_w[t * 4 + s];
        arow[t * 4 + s] = hrow;
      } else {
        arow[t * 4 + s] = -1;
      }
    }
  }
}

// ---------------- sparse GEMM1, 128x128 tile, BK=64, counted-vmcnt + asm ds_read ----------------
// R9-verified (107.5 us): chunked XCD swizzle (contiguous logical range per XCD -> A-tile
// fetched into one L2 once, FETCH 140->35 MB), LDS-coalesced epilogue, vmcnt(8) true wait,
// both-sides XOR swizzle (conflict-free), literal-offset asm ds_reads.
__global__ __launch_bounds__(256, 2) void gemm1_sp(const short* __restrict__ A,
                                                   const short* __restrict__ W1t,
                                                   const float* __restrict__ b1,
                                                   short* __restrict__ H,
                                                   const int* __restrict__ mlist,
                                                   const int* __restrict__ meta) {
  __shared__ __align__(16) short smem[32768];   // 64 KB: As | Bs, reused as Hs in epilogue
  short* As = smem;
  short* Bs = smem + 16384;
  unsigned nwg = gridDim.x * gridDim.y;                        // 8192
  unsigned hid = blockIdx.y * gridDim.x + blockIdx.x;
  unsigned lid = (hid & 7) * (nwg >> 3) + (hid >> 3);          // chunked XCD swizzle
  int xblk = lid & 15, yblk = lid >> 4;                        // gridDim.x == 16
  int e = yblk >> 6, j = yblk & 63;
  int cnt = meta[e];
  if (j * 128 >= cnt) return;
  int base = meta[8 + e];
  int tid = threadIdx.x, wave = tid >> 6, lane = tid & 63;
  int wm = wave >> 1, wn = wave & 1, quad = lane >> 4, l16 = lane & 15;
  int n0 = xblk * 128;
  const short* Bt = W1t + (size_t)e * DFF * DM;

  // staging: chunk c = q*256 + tid; row r = c>>3; logical slot s = (c&7)^(r&7) at source
  const short* agp[4]; const short* bgp[4];
  #pragma unroll
  for (int q = 0; q < 4; q++) {
    int c = q * 256 + tid;
    int r = c >> 3, s = (c & 7) ^ (r & 7);
    int rl = j * 128 + r;
    int tok = mlist[base + (rl < cnt ? rl : cnt - 1)];
    agp[q] = A + (size_t)tok * DM + s * 8;
    bgp[q] = Bt + (size_t)(n0 + r) * DM + s * 8;
  }

  f32x4 acc[4][4];
  #pragma unroll
  for (int i = 0; i < 4; i++)
    #pragma unroll
    for (int jj = 0; jj < 4; jj++) acc[i][jj] = (f32x4){0.f, 0.f, 0.f, 0.f};

  auto stage = [&](int bsel, int kt) {
    short* Ab = As + bsel * 8192 + wave * 512;
    short* Bb = Bs + bsel * 8192 + wave * 512;
    #pragma unroll
    for (int q = 0; q < 4; q++) {
      GLD_LDS16(agp[q] + kt, Ab + q * 2048);
      GLD_LDS16(bgp[q] + kt, Bb + q * 2048);
    }
  };

  stage(0, 0);
  stage(1, 64);

  // per-thread read bases (row stride 128 B); fragment rows differ by literal 2048 B
  unsigned aAddr0 = LDS_OFF(As) + (wm * 64 + l16) * 128;
  unsigned bAddr0 = LDS_OFF(Bs) + (wn * 64 + l16) * 128;
  unsigned soB[2];
  #pragma unroll
  for (int ks = 0; ks < 2; ks++) soB[ks] = (unsigned)((((ks << 2) | quad) ^ (l16 & 7)) << 4);

  const int NT = DM / 64;   // 8
  for (int t = 0; t < NT; t++) {
    if (t + 1 < NT) asm volatile("s_waitcnt vmcnt(8)" ::: "memory");
    else            asm volatile("s_waitcnt vmcnt(0)" ::: "memory");
    wg_barrier();              // tile t visible to all waves
    unsigned bo = (unsigned)((t & 1) * 16384);
    #pragma unroll
    for (int ks = 0; ks < 2; ks++) {
      unsigned aB = aAddr0 + bo + soB[ks];
      unsigned bB = bAddr0 + bo + soB[ks];
      bfrag afr[4], bfr[4];
      LDS_READ_OFF(afr[0], aB, "0");    LDS_READ_OFF(afr[1], aB, "2048");
      LDS_READ_OFF(afr[2], aB, "4096"); LDS_READ_OFF(afr[3], aB, "6144");
      LDS_READ_OFF(bfr[0], bB, "0");    LDS_READ_OFF(bfr[1], bB, "2048");
      LDS_READ_OFF(bfr[2], bB, "4096"); LDS_READ_OFF(bfr[3], bB, "6144");
      asm volatile("s_waitcnt lgkmcnt(0)" ::: "memory");
      __builtin_amdgcn_sched_barrier(0);
      __builtin_amdgcn_s_setprio(1);
      #pragma unroll
      for (int mi = 0; mi < 4; mi++)
        #pragma unroll
        for (int ni = 0; ni < 4; ni++)
          acc[mi][ni] = __builtin_amdgcn_mfma_f32_16x16x32_bf16(afr[mi], bfr[ni], acc[mi][ni], 0, 0, 0);
      __builtin_amdgcn_s_setprio(0);
    }
    wg_barrier();              // all waves done reading buf[t&1]
    if (t + 2 < NT) stage(t & 1, (t + 2) * 64);   // overwrite just-vacated buffer
  }

  // epilogue: gelu+bias -> LDS tile -> coalesced 16B stores
  short (*Hs)[136] = (short(*)[136])smem;   // 128*136*2 = 34816 B, LDS idle after loop
  const float* bb = b1 + (size_t)e * DFF;
  #pragma unroll
  for (int mi = 0; mi < 4; mi++) {
    int rl = wm * 64 + mi * 16 + quad * 4;
    #pragma unroll
    for (int ni = 0; ni < 4; ni++) {
      int cl = wn * 64 + ni * 16 + l16;
      float bv = bb[n0 + cl];
      #pragma unroll
      for (int r = 0; r < 4; r++)
        Hs[rl + r][cl] = f2bf(fast_gelu(acc[mi][ni][r] + bv));
    }
  }
  wg_barrier();
  int rbase0 = base + j * 128;
  int row16 = tid >> 4, colg = (tid & 15) * 8;
  #pragma unroll
  for (int ps = 0; ps < 8; ps++) {
    int row = ps * 16 + row16;
    u32x4 v = *(const u32x4*)&Hs[row][colg];
    *(u32x4*)(H + (size_t)(rbase0 + row) * DFF + n0 + colg) = v;
  }
}

// ---------------- sparse GEMM2, same structure, K=DFF ----------------
__global__ __launch_bounds__(256, 2) void gemm2_sp(const short* __restrict__ H,
                                                   const short* __restrict__ W2t,
                                                   const float* __restrict__ b2,
                                                   short* __restrict__ partial,
                                                   const float* __restrict__ wrow,
                                                   const int* __restrict__ meta) {
  __shared__ __align__(16) short smem[32768];
  short* As = smem;
  short* Bs = smem + 16384;
  unsigned nwg = gridDim.x * gridDim.y;                        // 2048
  unsigned hid = blockIdx.y * gridDim.x + blockIdx.x;
  unsigned lid = (hid & 7) * (nwg >> 3) + (hid >> 3);          // chunked XCD swizzle
  int xblk = lid & 3, yblk = lid >> 2;                         // gridDim.x == 4
  int e = yblk >> 6, j = yblk & 63;
  int cnt = meta[e];
  if (j * 128 >= cnt) return;
  int base = meta[8 + e];
  int tid = threadIdx.x, wave = tid >> 6, lane = tid & 63;
  int wm = wave >> 1, wn = wave & 1, quad = lane >> 4, l16 = lane & 15;
  int n0 = xblk * 128;
  const short* Bt = W2t + (size_t)e * DM * DFF;

  const short* agp[4]; const short* bgp[4];
  #pragma unroll
  for (int q = 0; q < 4; q++) {
    int c = q * 256 + tid;
    int r = c >> 3, s = (c & 7) ^ (r & 7);
    agp[q] = H + (size_t)(base + j * 128 + r) * DFF + s * 8;
    bgp[q] = Bt + (size_t)(n0 + r) * DFF + s * 8;
  }

  f32x4 acc[4][4];
  #pragma unroll
  for (int i = 0; i < 4; i++)
    #pragma unroll
    for (int jj = 0; jj < 4; jj++) acc[i][jj] = (f32x4){0.f, 0.f, 0.f, 0.f};

  auto stage = [&](int bsel, int kt) {
    short* Ab = As + bsel * 8192 + wave * 512;
    short* Bb = Bs + bsel * 8192 + wave * 512;
    #pragma unroll
    for (int q = 0; q < 4; q++) {
      GLD_LDS16(agp[q] + kt, Ab + q * 2048);
      GLD_LDS16(bgp[q] + kt, Bb + q * 2048);
    }
  };

  stage(0, 0);
  stage(1, 64);

  unsigned aAddr0 = LDS_OFF(As) + (wm * 64 + l16) * 128;
  unsigned bAddr0 = LDS_OFF(Bs) + (wn * 64 + l16) * 128;
  unsigned soB[2];
  #pragma unroll
  for (int ks = 0; ks < 2; ks++) soB[ks] = (unsigned)((((ks << 2) | quad) ^ (l16 & 7)) << 4);

  const int NT = DFF / 64;  // 32
  for (int t = 0; t < NT; t++) {
    if (t + 1 < NT) asm volatile("s_waitcnt vmcnt(8)" ::: "memory");
    else            asm volatile("s_waitcnt vmcnt(0)" ::: "memory");
    wg_barrier();
    unsigned bo = (unsigned)((t & 1) * 16384);
    #pragma unroll
    for (int ks = 0; ks < 2; ks++) {
      unsigned aB = aAddr0 + bo + soB[ks];
      unsigned bB = bAddr0 + bo + soB[ks];
      bfrag afr[4], bfr[4];
      LDS_READ_OFF(afr[0], aB, "0");    LDS_READ_OFF(afr[1], aB, "2048");
      LDS_READ_OFF(afr[2], aB, "4096"); LDS_READ_OFF(afr[3], aB, "6144");
      LDS_READ_OFF(bfr[0], bB, "0");    LDS_READ_OFF(bfr[1], bB, "2048");
      LDS_READ_OFF(bfr[2], bB, "4096"); LDS_READ_OFF(bfr[3], bB, "6144");
      asm volatile("s_waitcnt lgkmcnt(0)" ::: "memory");
      __builtin_amdgcn_sched_barrier(0);
      __builtin_amdgcn_s_setprio(1);
      #pragma unroll
      for (int mi = 0; mi < 4; mi++)
        #pragma unroll
        for (int ni = 0; ni < 4; ni++)
          acc[mi][ni] = __builtin_amdgcn_mfma_f32_16x16x32_bf16(afr[mi], bfr[ni], acc[mi][ni], 0, 0, 0);
      __builtin_amdgcn_s_setprio(0);
    }
    wg_barrier();
    if (t + 2 < NT) stage(t & 1, (t + 2) * 64);
  }

  // epilogue: w*(acc+bias) -> LDS tile -> coalesced 16B stores
  short (*Hs)[136] = (short(*)[136])smem;
  const float* bb = b2 + (size_t)e * DM;
  int rbase0 = base + j * 128;
  #pragma unroll
  for (int mi = 0; mi < 4; mi++) {
    int rl = wm * 64 + mi * 16 + quad * 4;
    #pragma unroll
    for (int ni = 0; ni < 4; ni++) {
      int cl = wn * 64 + ni * 16 + l16;
      float bv = bb[n0 + cl];
      #pragma unroll
      for (int r = 0; r < 4; r++) {
        float w = wrow[rbase0 + rl + r];
        Hs[rl + r][cl] = f2bf(w * (acc[mi][ni][r] + bv));
      }
    }
  }
  wg_barrier();
  int row16 = tid >> 4, colg = (tid & 15) * 8;
  #pragma unroll
  for (int ps = 0; ps < 8; ps++) {
    int row = ps * 16 + row16;
    u32x4 v = *(const u32x4*)&Hs[row][colg];
    *(u32x4*)(partial + (size_t)(rbase0 + row) * DM + n0 + colg) = v;
  }
}

// ---------------- combine ----------------
__global__ __launch_bounds__(256) void combine_kernel(const short* __restrict__ partial,
                                                      const int* __restrict__ arow,
                                                      float* __restrict__ out) {
  int gid = blockIdx.x * 256 + threadIdx.x;
  int t = gid >> 6, c0 = (gid & 63) << 3;
  const int* ar = arow + t * 4;
  float o[8];
  #pragma unroll
  for (int k = 0; k < 8; k++) o[k] = 0.f;
  #pragma unroll
  for (int s = 0; s < 4; s++) {
    int a = ar[s];
    if (a >= 0) {
      union { u32x4 v; short s16[8]; } buf;
      buf.v = *(const u32x4*)(partial + (size_t)a * DM + c0);
      #pragma unroll
      for (int k = 0; k < 8; k++) o[k] += bf2f(buf.s16[k]);
    }
  }
  float* op = out + (size_t)t * DM + c0;
  *(f32x4*)op = (f32x4){o[0], o[1], o[2], o[3]};
  *(f32x4*)(op + 4) = (f32x4){o[4], o[5], o[6], o[7]};
}

extern "C" void kernel_launch(void* const* d_in, const int* in_sizes, int n_in,
                              void* d_out, int out_size, void* d_ws, size_t ws_size,
                              hipStream_t stream) {
  const float* x  = (const float*)d_in[0];
  const float* rw = (const float*)d_in[1];
  const float* W1 = (const float*)d_in[2];
  const float* b1 = (const float*)d_in[3];
  const float* W2 = (const float*)d_in[4];
  const float* b2 = (const float*)d_in[5];
  float* out = (float*)d_out;

  char* base_p = (char*)d_ws; char* p = base_p;
  auto carve = [&](size_t bytes) { char* r = p; p += (bytes + 255) & ~(size_t)255; return r; };
  short* xb    = (short*)carve((size_t)NTOK * DM * 2);
  short* w1b   = (short*)carve((size_t)NE * DM * DFF * 2);  // [e][DFF][DM]
  short* w2b   = (short*)carve((size_t)NE * DFF * DM * 2);  // [e][DM][DFF]
  int*   sel_e = (int*)carve((size_t)NTOK * 4 * 4);
  float* sel_w = (float*)carve((size_t)NTOK * 4 * 4);
  float* part  = (float*)carve(256 * 16 * 4);
  int*   meta  = (int*)carve(64 * 4);
  int*   arow  = (int*)carve((size_t)NTOK * 4 * 4);
  int*   mlist = (int*)carve((size_t)ROWCAP * 4);
  float* wrow  = (float*)carve((size_t)ROWCAP * 4);
  short* Hbig  = (short*)carve((size_t)ROWCAP * DFF * 2);
  short* partial = (short*)carve((size_t)ROWCAP * DM * 2);

  cvtT2_kernel<<<dim3(512, NE * 2), 256, 0, stream>>>(W1, w1b, W2, w2b);
  router_kernel<<<256, 256, 0, stream>>>(x, rw, xb, sel_e, sel_w, part);
  prep_kernel<<<1, 256, 0, stream>>>(part, out + (size_t)NTOK * DM, meta);
  build_kernel<<<256, 256, 0, stream>>>(sel_e, sel_w, meta, mlist, wrow, arow);
  gemm1_sp<<<dim3(DFF / 128, NE * 64), 256, 0, stream>>>(xb, w1b, b1, Hbig, mlist, meta);
  gemm2_sp<<<dim3(DM / 128, NE * 64), 256, 0, stream>>>(Hbig, w2b, b2, partial, wrow, meta);
  combine_kernel<<<NTOK * DM / 8 / 256, 256, 0, stream>>>(partial, arow, out);
}